// Round 1
// baseline (1687.587 us; speedup 1.0000x reference)
//
#include <hip/hip_runtime.h>
#include <cstddef>

// ---------------------------------------------------------------------------
// Problem constants (B=2, S=2048, D_MODEL=1024, H=16, DEPTH=64)
// ---------------------------------------------------------------------------
#define BS      2
#define SEQ     2048
#define DM      1024
#define NH      16
#define DEPTH   64
#define ROWS    (BS*SEQ)          // 4096 rows of (B*S, D_MODEL)
#define BHS     (BS*NH*SEQ)       // 65536 (b,h,s) rows

// ---------------------------------------------------------------------------
// GEMM: C[M,N] = A[M,K] @ W[K,N] + bias[N]   (all fp32 row-major)
// Tile 128x64, BK=16, 256 threads, 8x4 per thread.
// ---------------------------------------------------------------------------
__global__ __launch_bounds__(256) void gemm_bias_kernel(
    const float* __restrict__ A, const float* __restrict__ W,
    const float* __restrict__ bias, float* __restrict__ C,
    int M, int N, int K)
{
    __shared__ float As[16][128];   // [k][m]
    __shared__ float Bsh[16][64];   // [k][n]
    const int tid = threadIdx.x;
    const int tr  = tid >> 4;       // 0..15
    const int tc  = tid & 15;       // 0..15
    const int row0 = blockIdx.y * 128;
    const int col0 = blockIdx.x * 64;

    float acc[8][4];
#pragma unroll
    for (int i = 0; i < 8; ++i)
#pragma unroll
        for (int j = 0; j < 4; ++j) acc[i][j] = 0.0f;

    for (int k0 = 0; k0 < K; k0 += 16) {
        // A tile: 128 rows x 16 cols -> transposed into As[k][m]
#pragma unroll
        for (int ii = 0; ii < 2; ++ii) {
            int idx = tid * 2 + ii;           // 0..511 float4 slots
            int r = idx >> 2;                 // 0..127
            int c = (idx & 3) * 4;            // 0,4,8,12
            float4 v = *(const float4*)&A[(size_t)(row0 + r) * K + k0 + c];
            As[c+0][r] = v.x; As[c+1][r] = v.y; As[c+2][r] = v.z; As[c+3][r] = v.w;
        }
        {
            int r = tid >> 4;                 // 0..15
            int c = (tid & 15) * 4;           // 0..60
            *(float4*)&Bsh[r][c] = *(const float4*)&W[(size_t)(k0 + r) * N + col0 + c];
        }
        __syncthreads();
#pragma unroll
        for (int kk = 0; kk < 16; ++kk) {
            float4 a0 = *(const float4*)&As[kk][tr*4];
            float4 a1 = *(const float4*)&As[kk][tr*4 + 64];
            float4 b  = *(const float4*)&Bsh[kk][tc*4];
            float a[8] = {a0.x,a0.y,a0.z,a0.w,a1.x,a1.y,a1.z,a1.w};
            float bb[4] = {b.x,b.y,b.z,b.w};
#pragma unroll
            for (int i = 0; i < 8; ++i)
#pragma unroll
                for (int j = 0; j < 4; ++j)
                    acc[i][j] = fmaf(a[i], bb[j], acc[i][j]);
        }
        __syncthreads();
    }

    float4 bv = *(const float4*)&bias[col0 + tc*4];
#pragma unroll
    for (int i = 0; i < 8; ++i) {
        int r = row0 + (i < 4 ? tr*4 + i : tr*4 + 64 + (i - 4));
        float4 o;
        o.x = acc[i][0] + bv.x; o.y = acc[i][1] + bv.y;
        o.z = acc[i][2] + bv.z; o.w = acc[i][3] + bv.w;
        *(float4*)&C[(size_t)r * N + col0 + tc*4] = o;
    }
}

// ---------------------------------------------------------------------------
// Fused LayerNorm -> per-head softmax.
// MODE 0 (Q): out = softmax prob (BHSD layout), ENT[b,h,s] = sum p*log p
// MODE 1 (K): out = log(softmax prob + 2e-8)  (BHSD layout)
// MODE 2 (V): out = LN result (BHSD layout)
// One block per row (b,s); 256 threads; thread t owns elements 4t..4t+3;
// 16 consecutive lanes own one head (64 elems) -> shfl width-16 reductions.
// ---------------------------------------------------------------------------
template<int MODE>
__global__ __launch_bounds__(256) void ln_head_kernel(
    const float* __restrict__ X, const float* __restrict__ G,
    const float* __restrict__ Bt, float* __restrict__ OUT,
    float* __restrict__ ENT)
{
    const int row = blockIdx.x;           // 0..4095 = b*SEQ + s
    const int tid = threadIdx.x;
    const float* x = X + (size_t)row * DM;
    float4 v = *(const float4*)&x[tid*4];

    float s  = v.x + v.y + v.z + v.w;
    float ss = v.x*v.x + v.y*v.y + v.z*v.z + v.w*v.w;
#pragma unroll
    for (int m = 1; m < 64; m <<= 1) { s += __shfl_xor(s, m); ss += __shfl_xor(ss, m); }
    __shared__ float redS[4], redQ[4];
    const int wave = tid >> 6, lane = tid & 63;
    if (lane == 0) { redS[wave] = s; redQ[wave] = ss; }
    __syncthreads();
    s  = redS[0] + redS[1] + redS[2] + redS[3];
    ss = redQ[0] + redQ[1] + redQ[2] + redQ[3];
    const float mu   = s * (1.0f / DM);
    const float var  = ss * (1.0f / DM) - mu * mu;
    const float rsig = rsqrtf(var + 1e-6f);

    float4 gv = *(const float4*)&G[tid*4];
    float4 bv = *(const float4*)&Bt[tid*4];
    float y0 = (v.x - mu) * rsig * gv.x + bv.x;
    float y1 = (v.y - mu) * rsig * gv.y + bv.y;
    float y2 = (v.z - mu) * rsig * gv.z + bv.z;
    float y3 = (v.w - mu) * rsig * gv.w + bv.w;

    const int b  = row >> 11;             // /SEQ
    const int sl = row & (SEQ - 1);
    const int h  = tid >> 4;              // head
    const size_t obase = (((size_t)(b*NH + h)) * SEQ + sl) * DEPTH + (tid & 15) * 4;

    if constexpr (MODE == 2) {
        *(float4*)&OUT[obase] = make_float4(y0, y1, y2, y3);
    } else {
        float mx = fmaxf(fmaxf(y0, y1), fmaxf(y2, y3));
#pragma unroll
        for (int m = 1; m < 16; m <<= 1) mx = fmaxf(mx, __shfl_xor(mx, m, 16));
        float e0 = expf(y0 - mx), e1 = expf(y1 - mx), e2 = expf(y2 - mx), e3 = expf(y3 - mx);
        float se = e0 + e1 + e2 + e3;
#pragma unroll
        for (int m = 1; m < 16; m <<= 1) se += __shfl_xor(se, m, 16);
        float inv = 1.0f / se;
        float p0 = e0*inv, p1 = e1*inv, p2 = e2*inv, p3 = e3*inv;
        if constexpr (MODE == 0) {
            *(float4*)&OUT[obase] = make_float4(p0, p1, p2, p3);
            float lse = logf(se);
            float el = p0*(y0-mx-lse) + p1*(y1-mx-lse) + p2*(y2-mx-lse) + p3*(y3-mx-lse);
#pragma unroll
            for (int m = 1; m < 16; m <<= 1) el += __shfl_xor(el, m, 16);
            if ((tid & 15) == 0) ENT[((size_t)(b*NH + h)) * SEQ + sl] = el;
        } else {
            *(float4*)&OUT[obase] = make_float4(logf(p0 + 2e-8f), logf(p1 + 2e-8f),
                                                logf(p2 + 2e-8f), logf(p3 + 2e-8f));
        }
    }
}

// ---------------------------------------------------------------------------
// Attention: per (b,h), 32 q-rows per block, k in chunks of 64.
// scores = ent - QP @ LK^T ; x = scores/8 ; csch = 2/(expm1(x)-expm1(-x))
// Writes UNNORMALIZED csch to ATTN, rowsum to RS, csch@V (unnormalized) to OV.
// Thread map: kg = tid&15 (4 k-cols), qg = tid>>4 (2 q-rows).
// ---------------------------------------------------------------------------
__global__ __launch_bounds__(256) void attn_kernel(
    const float* __restrict__ QP, const float* __restrict__ LK,
    const float* __restrict__ VH, const float* __restrict__ ENT,
    float* __restrict__ ATTN, float* __restrict__ RS, float* __restrict__ OV)
{
    const int bh = blockIdx.y;            // 0..31
    const int q0 = blockIdx.x * 32;
    const int tid = threadIdx.x;
    const int kg = tid & 15;
    const int qg = tid >> 4;
    const size_t rowbase = (size_t)bh * SEQ;

    __shared__ float Qt[DEPTH][36];       // [d][q] (transposed)
    __shared__ float Kt[DEPTH][68];       // [d][k] (transposed chunk)
    __shared__ float Vs[64][68];          // [k][d]
    __shared__ float Cs[32][68];          // [q][k] csch chunk
    __shared__ float ent_s[32];

    {
        int q  = tid >> 3;                // 0..31
        int d0 = (tid & 7) * 8;           // 0..56
        const float* src = &QP[(rowbase + q0 + q) * DEPTH + d0];
        float4 a = *(const float4*)src;
        float4 b = *(const float4*)(src + 4);
        Qt[d0+0][q] = a.x; Qt[d0+1][q] = a.y; Qt[d0+2][q] = a.z; Qt[d0+3][q] = a.w;
        Qt[d0+4][q] = b.x; Qt[d0+5][q] = b.y; Qt[d0+6][q] = b.z; Qt[d0+7][q] = b.w;
    }
    if (tid < 32) ent_s[tid] = ENT[rowbase + q0 + tid];

    float av0[4] = {0,0,0,0}, av1[4] = {0,0,0,0};
    float rs0 = 0.0f, rs1 = 0.0f;

    for (int k0 = 0; k0 < SEQ; k0 += 64) {
        __syncthreads();   // protect LDS reuse across iterations (also covers Qt/ent_s init)
#pragma unroll
        for (int ii = 0; ii < 4; ++ii) {
            int i  = tid + ii * 256;      // 0..1023 float4 slots
            int r  = i >> 4;              // 0..63
            int d0 = (i & 15) * 4;
            float4 kv = *(const float4*)&LK[(rowbase + k0 + r) * DEPTH + d0];
            Kt[d0+0][r] = kv.x; Kt[d0+1][r] = kv.y; Kt[d0+2][r] = kv.z; Kt[d0+3][r] = kv.w;
            float4 vv = *(const float4*)&VH[(rowbase + k0 + r) * DEPTH + d0];
            *(float4*)&Vs[r][d0] = vv;
        }
        __syncthreads();

        float acc0[4] = {0,0,0,0}, acc1[4] = {0,0,0,0};
#pragma unroll
        for (int d = 0; d < DEPTH; ++d) {
            float4 kv = *(const float4*)&Kt[d][kg*4];
            float qa = Qt[d][qg*2];
            float qb = Qt[d][qg*2+1];
            acc0[0] = fmaf(qa, kv.x, acc0[0]); acc0[1] = fmaf(qa, kv.y, acc0[1]);
            acc0[2] = fmaf(qa, kv.z, acc0[2]); acc0[3] = fmaf(qa, kv.w, acc0[3]);
            acc1[0] = fmaf(qb, kv.x, acc1[0]); acc1[1] = fmaf(qb, kv.y, acc1[1]);
            acc1[2] = fmaf(qb, kv.z, acc1[2]); acc1[3] = fmaf(qb, kv.w, acc1[3]);
        }

        const float ea = ent_s[qg*2], eb = ent_s[qg*2+1];
        float c0[4], c1[4];
#pragma unroll
        for (int j = 0; j < 4; ++j) {
            float xa = (ea - acc0[j]) * 0.125f;
            c0[j] = 2.0f / (expm1f(xa) - expm1f(-xa));
            float xb = (eb - acc1[j]) * 0.125f;
            c1[j] = 2.0f / (expm1f(xb) - expm1f(-xb));
        }

        *(float4*)&ATTN[(rowbase + q0 + qg*2    ) * SEQ + k0 + kg*4] = make_float4(c0[0],c0[1],c0[2],c0[3]);
        *(float4*)&ATTN[(rowbase + q0 + qg*2 + 1) * SEQ + k0 + kg*4] = make_float4(c1[0],c1[1],c1[2],c1[3]);

        float ps0 = c0[0]+c0[1]+c0[2]+c0[3];
        float ps1 = c1[0]+c1[1]+c1[2]+c1[3];
#pragma unroll
        for (int m = 1; m < 16; m <<= 1) { ps0 += __shfl_xor(ps0, m, 16); ps1 += __shfl_xor(ps1, m, 16); }
        rs0 += ps0; rs1 += ps1;

        *(float4*)&Cs[qg*2  ][kg*4] = make_float4(c0[0],c0[1],c0[2],c0[3]);
        *(float4*)&Cs[qg*2+1][kg*4] = make_float4(c1[0],c1[1],c1[2],c1[3]);
        __syncthreads();

#pragma unroll
        for (int kk = 0; kk < 64; ++kk) {
            float4 vv = *(const float4*)&Vs[kk][kg*4];
            float ca = Cs[qg*2][kk];
            float cb = Cs[qg*2+1][kk];
            av0[0] = fmaf(ca, vv.x, av0[0]); av0[1] = fmaf(ca, vv.y, av0[1]);
            av0[2] = fmaf(ca, vv.z, av0[2]); av0[3] = fmaf(ca, vv.w, av0[3]);
            av1[0] = fmaf(cb, vv.x, av1[0]); av1[1] = fmaf(cb, vv.y, av1[1]);
            av1[2] = fmaf(cb, vv.z, av1[2]); av1[3] = fmaf(cb, vv.w, av1[3]);
        }
    }

    if (kg == 0) {
        RS[rowbase + q0 + qg*2    ] = rs0;
        RS[rowbase + q0 + qg*2 + 1] = rs1;
    }
    *(float4*)&OV[(rowbase + q0 + qg*2    ) * DEPTH + kg*4] = make_float4(av0[0],av0[1],av0[2],av0[3]);
    *(float4*)&OV[(rowbase + q0 + qg*2 + 1) * DEPTH + kg*4] = make_float4(av1[0],av1[1],av1[2],av1[3]);
}

// ---------------------------------------------------------------------------
// Normalize attn in place: attn[row, k] /= RS[row]
// ---------------------------------------------------------------------------
__global__ __launch_bounds__(256) void attn_norm_kernel(
    float* __restrict__ ATTN, const float* __restrict__ RS)
{
    size_t i = (size_t)blockIdx.x * 256 + threadIdx.x;   // float4 index
    float inv = 1.0f / RS[i >> 9];                        // row = i*4/2048
    float4* p = (float4*)ATTN;
    float4 v = p[i];
    v.x *= inv; v.y *= inv; v.z *= inv; v.w *= inv;
    p[i] = v;
}

// ---------------------------------------------------------------------------
// OV (BHSD, unnormalized) -> OUTN ((B*S) x D_MODEL row-major), divided by RS
// ---------------------------------------------------------------------------
__global__ __launch_bounds__(256) void finalize_ov_kernel(
    const float* __restrict__ OV, const float* __restrict__ RS,
    float* __restrict__ OUTN)
{
    int i = blockIdx.x * 256 + threadIdx.x;   // float4 index over 1M
    int flat = i * 4;
    int bh  = flat >> 17;                     // /(SEQ*DEPTH)
    int rem = flat & (SEQ*DEPTH - 1);
    int s   = rem >> 6;
    int d   = rem & (DEPTH - 1);
    float inv = 1.0f / RS[bh * SEQ + s];
    float4 v = ((const float4*)OV)[i];
    v.x *= inv; v.y *= inv; v.z *= inv; v.w *= inv;
    int b = bh >> 4, h = bh & (NH - 1);
    size_t o = ((size_t)(b * SEQ + s)) * DM + h * DEPTH + d;
    *(float4*)&OUTN[o] = v;
}

// ---------------------------------------------------------------------------
extern "C" void kernel_launch(void* const* d_in, const int* in_sizes, int n_in,
                              void* d_out, int out_size, void* d_ws, size_t ws_size,
                              hipStream_t stream)
{
    const float* q_in = (const float*)d_in[0];
    const float* k_in = (const float*)d_in[1];
    const float* Wq = (const float*)d_in[2];
    const float* bq = (const float*)d_in[3];
    const float* Wk = (const float*)d_in[4];
    const float* bk = (const float*)d_in[5];
    const float* Wv = (const float*)d_in[6];
    const float* bvp = (const float*)d_in[7];
    const float* Wo = (const float*)d_in[8];
    const float* bo = (const float*)d_in[9];
    const float* g1 = (const float*)d_in[10];
    const float* b1 = (const float*)d_in[11];
    const float* g2 = (const float*)d_in[12];
    const float* b2 = (const float*)d_in[13];
    const float* g3 = (const float*)d_in[14];
    const float* b3 = (const float*)d_in[15];

    float* out0 = (float*)d_out;                         // (B,S,DM) = 4,194,304
    float* attn = out0 + (size_t)ROWS * DM;              // (B,H,S,S) = 134,217,728

    float* ws = (float*)d_ws;
    const size_t SL = (size_t)ROWS * DM;                 // 4M floats per slot
    float* s0 = ws;
    float* s1 = ws + SL;
    float* s2 = ws + 2*SL;
    float* s3 = ws + 3*SL;
    float* ent = ws + 4*SL;                              // 65536
    float* rs  = ent + BHS;                              // 65536

    dim3 gg(DM/64, ROWS/128);                            // (16, 32)
    // q1 = q_in@Wq+bq ; q2 = q1@Wq+bq
    gemm_bias_kernel<<<gg, 256, 0, stream>>>(q_in, Wq, bq, s0, ROWS, DM, DM);
    gemm_bias_kernel<<<gg, 256, 0, stream>>>(s0,  Wq, bq, s1, ROWS, DM, DM);
    // k1 = k_in@Wk+bk ; k2 = k1@Wk+bk ; v1 = k1@Wv+bv
    gemm_bias_kernel<<<gg, 256, 0, stream>>>(k_in, Wk, bk, s2, ROWS, DM, DM);
    gemm_bias_kernel<<<gg, 256, 0, stream>>>(s2,  Wk, bk, s0, ROWS, DM, DM);
    gemm_bias_kernel<<<gg, 256, 0, stream>>>(s2,  Wv, bvp, s3, ROWS, DM, DM);
    // LN + head softmax
    ln_head_kernel<0><<<ROWS, 256, 0, stream>>>(s1, g1, b1, s2, ent);      // q_prob -> s2
    ln_head_kernel<1><<<ROWS, 256, 0, stream>>>(s0, g2, b2, s1, nullptr);  // logk   -> s1
    ln_head_kernel<2><<<ROWS, 256, 0, stream>>>(s3, g3, b3, s0, nullptr);  // v      -> s0
    // attention core: csch (unnormalized) -> attn, rowsums -> rs, csch@V -> s3
    attn_kernel<<<dim3(SEQ/32, BS*NH), 256, 0, stream>>>(s2, s1, s0, ent, attn, rs, s3);
    // normalize attn in place
    attn_norm_kernel<<<(BS*NH*(size_t)SEQ*SEQ)/(4*256), 256, 0, stream>>>(attn, rs);
    // out rows (B*S, DM) <- OV/rowsum
    finalize_ov_kernel<<<(ROWS*DM)/(4*256), 256, 0, stream>>>(s3, rs, s1);
    // final projection
    gemm_bias_kernel<<<gg, 256, 0, stream>>>(s1, Wo, bo, out0, ROWS, DM, DM);
}

// Round 2
// 1078.207 us; speedup vs baseline: 1.5652x; 1.5652x over previous
//
#include <hip/hip_runtime.h>
#include <cstddef>

#define BS      2
#define SEQ     2048
#define DM      1024
#define NH      16
#define DEPTH   64
#define ROWS    (BS*SEQ)          // 4096
#define BHS     (BS*NH*SEQ)       // 65536

typedef unsigned short u16;
typedef __attribute__((ext_vector_type(8))) short short8v;
typedef __attribute__((ext_vector_type(4))) float f32x4;

__device__ __forceinline__ u16 f2bf(float x) {
    unsigned u = __builtin_bit_cast(unsigned, x);
    unsigned r = u + 0x7FFFu + ((u >> 16) & 1u);
    return (u16)(r >> 16);
}
__device__ __forceinline__ float bf2f(u16 h) {
    unsigned u = ((unsigned)h) << 16;
    return __builtin_bit_cast(float, u);
}

// ---------------------------------------------------------------------------
// Weight transpose + split: W[K][N] fp32 -> Wt hi/lo [N][K] bf16
// ---------------------------------------------------------------------------
__global__ __launch_bounds__(256) void wsplit_kernel(
    const float* __restrict__ W, u16* __restrict__ H, u16* __restrict__ L)
{
    __shared__ float tile[32][33];
    const int bn = blockIdx.x, bk = blockIdx.y;
    const int c = threadIdx.x & 31, r0 = threadIdx.x >> 5;   // 8 rows/pass
#pragma unroll
    for (int r = 0; r < 32; r += 8)
        tile[r0 + r][c] = W[(size_t)(bk*32 + r0 + r) * DM + bn*32 + c];
    __syncthreads();
#pragma unroll
    for (int r = 0; r < 32; r += 8) {
        float v = tile[c][r0 + r];
        u16 h = f2bf(v);
        size_t o = (size_t)(bn*32 + r0 + r) * DM + bk*32 + c;
        H[o] = h;
        L[o] = f2bf(v - bf2f(h));
    }
}

// ---------------------------------------------------------------------------
// Elementwise split fp32 -> bf16 hi/lo
// ---------------------------------------------------------------------------
__global__ __launch_bounds__(256) void split_kernel(
    const float* __restrict__ X, u16* __restrict__ H, u16* __restrict__ L)
{
    int i = blockIdx.x * 256 + threadIdx.x;        // float4 index
    float4 v = ((const float4*)X)[i];
    u16 h0 = f2bf(v.x), h1 = f2bf(v.y), h2 = f2bf(v.z), h3 = f2bf(v.w);
    u16 l0 = f2bf(v.x - bf2f(h0)), l1 = f2bf(v.y - bf2f(h1));
    u16 l2 = f2bf(v.z - bf2f(h2)), l3 = f2bf(v.w - bf2f(h3));
    uint2 hh, ll;
    hh.x = (unsigned)h0 | ((unsigned)h1 << 16); hh.y = (unsigned)h2 | ((unsigned)h3 << 16);
    ll.x = (unsigned)l0 | ((unsigned)l1 << 16); ll.y = (unsigned)l2 | ((unsigned)l3 << 16);
    ((uint2*)H)[i] = hh;
    ((uint2*)L)[i] = ll;
}

// ---------------------------------------------------------------------------
// Split-bf16 MFMA GEMM: C[M=4096][N=1024] = A@W + bias
// A given as (Ah,Al) M x K bf16 row-major; W as (Bh,Bl) N x K bf16 (pre-transposed).
// C = Ah*Bh + Ah*Bl + Al*Bh (fp32 acc) -- fp32-grade accuracy.
// Tile 128(M) x 64(N), BK=32, 256 threads = 4 waves (2x2), wave tile 64x32,
// per-wave frags 4x2 of 16x16. OUT_MODE 0: fp32 C; 1: split (Ch,Cl) only.
// ---------------------------------------------------------------------------
template<int OUT_MODE>
__global__ __launch_bounds__(256) void gemm_mfma(
    const u16* __restrict__ Ah, const u16* __restrict__ Al,
    const u16* __restrict__ Bh, const u16* __restrict__ Bl,
    const float* __restrict__ bias, float* __restrict__ C,
    u16* __restrict__ Ch, u16* __restrict__ Cl)
{
    constexpr int K = 1024, N = 1024;
    __shared__ u16 AsH[128*40], AsL[128*40], BsH[64*40], BsL[64*40];

    const int t = threadIdx.x;
    const int m0 = blockIdx.y * 128;
    const int n0 = blockIdx.x * 64;
    const int lane = t & 63, w = t >> 6;
    const int wr = w >> 1, wc = w & 1;
    const int lr = lane & 15, lk = lane >> 4;

    f32x4 acc[4][2];
#pragma unroll
    for (int i = 0; i < 4; ++i)
#pragma unroll
        for (int j = 0; j < 2; ++j) acc[i][j] = (f32x4){0.f,0.f,0.f,0.f};

    for (int k0 = 0; k0 < K; k0 += 32) {
        __syncthreads();
#pragma unroll
        for (int r = 0; r < 2; ++r) {
            int s = r*256 + t;
            int row = s >> 2, c = s & 3;
            size_t g = (size_t)(m0 + row) * K + k0 + c*8;
            *(short8v*)&AsH[row*40 + c*8] = *(const short8v*)&Ah[g];
            *(short8v*)&AsL[row*40 + c*8] = *(const short8v*)&Al[g];
        }
        {
            int row = t >> 2, c = t & 3;
            size_t g = (size_t)(n0 + row) * K + k0 + c*8;
            *(short8v*)&BsH[row*40 + c*8] = *(const short8v*)&Bh[g];
            *(short8v*)&BsL[row*40 + c*8] = *(const short8v*)&Bl[g];
        }
        __syncthreads();

        short8v ah[4], al[4], bh[2], bl[2];
#pragma unroll
        for (int i = 0; i < 4; ++i) {
            int off = (wr*64 + i*16 + lr)*40 + lk*8;
            ah[i] = *(const short8v*)&AsH[off];
            al[i] = *(const short8v*)&AsL[off];
        }
#pragma unroll
        for (int j = 0; j < 2; ++j) {
            int off = (wc*32 + j*16 + lr)*40 + lk*8;
            bh[j] = *(const short8v*)&BsH[off];
            bl[j] = *(const short8v*)&BsL[off];
        }
#pragma unroll
        for (int i = 0; i < 4; ++i)
#pragma unroll
            for (int j = 0; j < 2; ++j) {
                acc[i][j] = __builtin_amdgcn_mfma_f32_16x16x32_bf16(ah[i], bh[j], acc[i][j], 0, 0, 0);
                acc[i][j] = __builtin_amdgcn_mfma_f32_16x16x32_bf16(ah[i], bl[j], acc[i][j], 0, 0, 0);
                acc[i][j] = __builtin_amdgcn_mfma_f32_16x16x32_bf16(al[i], bh[j], acc[i][j], 0, 0, 0);
            }
    }

    // epilogue: C/D layout col = lane&15, row = (lane>>4)*4 + r
    float bj[2];
#pragma unroll
    for (int j = 0; j < 2; ++j) bj[j] = bias[n0 + wc*32 + j*16 + lr];
#pragma unroll
    for (int i = 0; i < 4; ++i)
#pragma unroll
        for (int j = 0; j < 2; ++j) {
            int col = n0 + wc*32 + j*16 + lr;
#pragma unroll
            for (int r = 0; r < 4; ++r) {
                int row = m0 + wr*64 + i*16 + lk*4 + r;
                float v = acc[i][j][r] + bj[j];
                size_t o = (size_t)row * N + col;
                if constexpr (OUT_MODE == 0) {
                    C[o] = v;
                } else {
                    u16 h = f2bf(v);
                    Ch[o] = h;
                    Cl[o] = f2bf(v - bf2f(h));
                }
            }
        }
}

// ---------------------------------------------------------------------------
// Fused LayerNorm -> per-head softmax (unchanged from r1).
// MODE 0: q_prob + entropy ; MODE 1: log(prob+eps) ; MODE 2: plain LN. BHSD out.
// ---------------------------------------------------------------------------
template<int MODE>
__global__ __launch_bounds__(256) void ln_head_kernel(
    const float* __restrict__ X, const float* __restrict__ G,
    const float* __restrict__ Bt, float* __restrict__ OUT,
    float* __restrict__ ENT)
{
    const int row = blockIdx.x;
    const int tid = threadIdx.x;
    const float* x = X + (size_t)row * DM;
    float4 v = *(const float4*)&x[tid*4];

    float s  = v.x + v.y + v.z + v.w;
    float ss = v.x*v.x + v.y*v.y + v.z*v.z + v.w*v.w;
#pragma unroll
    for (int m = 1; m < 64; m <<= 1) { s += __shfl_xor(s, m); ss += __shfl_xor(ss, m); }
    __shared__ float redS[4], redQ[4];
    const int wave = tid >> 6, lane = tid & 63;
    if (lane == 0) { redS[wave] = s; redQ[wave] = ss; }
    __syncthreads();
    s  = redS[0] + redS[1] + redS[2] + redS[3];
    ss = redQ[0] + redQ[1] + redQ[2] + redQ[3];
    const float mu   = s * (1.0f / DM);
    const float var  = ss * (1.0f / DM) - mu * mu;
    const float rsig = rsqrtf(var + 1e-6f);

    float4 gv = *(const float4*)&G[tid*4];
    float4 bv = *(const float4*)&Bt[tid*4];
    float y0 = (v.x - mu) * rsig * gv.x + bv.x;
    float y1 = (v.y - mu) * rsig * gv.y + bv.y;
    float y2 = (v.z - mu) * rsig * gv.z + bv.z;
    float y3 = (v.w - mu) * rsig * gv.w + bv.w;

    const int b  = row >> 11;
    const int sl = row & (SEQ - 1);
    const int h  = tid >> 4;
    const size_t obase = (((size_t)(b*NH + h)) * SEQ + sl) * DEPTH + (tid & 15) * 4;

    if constexpr (MODE == 2) {
        *(float4*)&OUT[obase] = make_float4(y0, y1, y2, y3);
    } else {
        float mx = fmaxf(fmaxf(y0, y1), fmaxf(y2, y3));
#pragma unroll
        for (int m = 1; m < 16; m <<= 1) mx = fmaxf(mx, __shfl_xor(mx, m, 16));
        float e0 = expf(y0 - mx), e1 = expf(y1 - mx), e2 = expf(y2 - mx), e3 = expf(y3 - mx);
        float se = e0 + e1 + e2 + e3;
#pragma unroll
        for (int m = 1; m < 16; m <<= 1) se += __shfl_xor(se, m, 16);
        float inv = 1.0f / se;
        float p0 = e0*inv, p1 = e1*inv, p2 = e2*inv, p3 = e3*inv;
        if constexpr (MODE == 0) {
            *(float4*)&OUT[obase] = make_float4(p0, p1, p2, p3);
            float lse = logf(se);
            float el = p0*(y0-mx-lse) + p1*(y1-mx-lse) + p2*(y2-mx-lse) + p3*(y3-mx-lse);
#pragma unroll
            for (int m = 1; m < 16; m <<= 1) el += __shfl_xor(el, m, 16);
            if ((tid & 15) == 0) ENT[((size_t)(b*NH + h)) * SEQ + sl] = el;
        } else {
            *(float4*)&OUT[obase] = make_float4(logf(p0 + 2e-8f), logf(p1 + 2e-8f),
                                                logf(p2 + 2e-8f), logf(p3 + 2e-8f));
        }
    }
}

// ---------------------------------------------------------------------------
// Attention v2: per (b,h), BQ=64 q rows/block, k chunks of 64.
// Per-thread 4q x 4k outer product (QK) and 4q x 4d (PV).
// qg = tid&15 (4 q rows), kg = tid>>4 (4 k cols / 4 d cols).
// Writes unnormalized csch to ATTN, rowsums to RS, csch@V to OV.
// ---------------------------------------------------------------------------
__global__ __launch_bounds__(256) void attn2_kernel(
    const float* __restrict__ QP, const float* __restrict__ LK,
    const float* __restrict__ VH, const float* __restrict__ ENT,
    float* __restrict__ ATTN, float* __restrict__ RS, float* __restrict__ OV)
{
    const int bh  = blockIdx.y;
    const int q0  = blockIdx.x * 64;
    const int tid = threadIdx.x;
    const int qg  = tid & 15;
    const int kg  = tid >> 4;
    const int w   = tid >> 6;
    const size_t rowbase = (size_t)bh * SEQ;

    __shared__ float Qt[64][68];    // [d][q]
    __shared__ float KC[64][68];    // [d][k] during QK, then Cs[k][q] for PV
    __shared__ float Vs[64][68];    // [k][d]
    __shared__ float ent_s[64];
    __shared__ float rs_part[4][64];

    // stage Q (transposed) once
#pragma unroll
    for (int r = 0; r < 4; ++r) {
        int s = r*256 + tid;            // 1024 float4 slots
        int q = s >> 4, d0 = (s & 15) * 4;
        float4 qv = *(const float4*)&QP[(rowbase + q0 + q) * DEPTH + d0];
        Qt[d0+0][q] = qv.x; Qt[d0+1][q] = qv.y; Qt[d0+2][q] = qv.z; Qt[d0+3][q] = qv.w;
    }
    if (tid < 64) ent_s[tid] = ENT[rowbase + q0 + tid];

    float e_q[4];
    float av[4][4];
#pragma unroll
    for (int i = 0; i < 4; ++i)
#pragma unroll
        for (int j = 0; j < 4; ++j) av[i][j] = 0.0f;
    float rsum[4] = {0,0,0,0};

    bool efirst = true;

    for (int k0 = 0; k0 < SEQ; k0 += 64) {
        __syncthreads();     // prev PV done (also covers Qt/ent staging on iter 0)
        if (efirst) {
            // ent_s valid only after first barrier
        }
        // stage K (transposed) and V
#pragma unroll
        for (int r = 0; r < 4; ++r) {
            int s = r*256 + tid;
            int kr = s >> 4, d0 = (s & 15) * 4;
            float4 kv = *(const float4*)&LK[(rowbase + k0 + kr) * DEPTH + d0];
            KC[d0+0][kr] = kv.x; KC[d0+1][kr] = kv.y; KC[d0+2][kr] = kv.z; KC[d0+3][kr] = kv.w;
            *(float4*)&Vs[kr][d0] = *(const float4*)&VH[(rowbase + k0 + kr) * DEPTH + d0];
        }
        __syncthreads();
        if (efirst) {
            efirst = false;
#pragma unroll
            for (int i = 0; i < 4; ++i) e_q[i] = ent_s[qg*4 + i];
        }

        // QK: acc[i][j] = sum_d Qt[d][qg*4+i] * Kt[d][kg*4+j]
        float acc[4][4];
#pragma unroll
        for (int i = 0; i < 4; ++i)
#pragma unroll
            for (int j = 0; j < 4; ++j) acc[i][j] = 0.0f;
#pragma unroll 8
        for (int d = 0; d < DEPTH; ++d) {
            float4 qv = *(const float4*)&Qt[d][qg*4];
            float4 kv = *(const float4*)&KC[d][kg*4];
            float qa[4] = {qv.x, qv.y, qv.z, qv.w};
            float ka[4] = {kv.x, kv.y, kv.z, kv.w};
#pragma unroll
            for (int i = 0; i < 4; ++i)
#pragma unroll
                for (int j = 0; j < 4; ++j)
                    acc[i][j] = fmaf(qa[i], ka[j], acc[i][j]);
        }

        // csch + attn write + rowsum
        float cs[4][4];
#pragma unroll
        for (int i = 0; i < 4; ++i) {
#pragma unroll
            for (int j = 0; j < 4; ++j) {
                float x = (e_q[i] - acc[i][j]) * 0.125f;
                float u = expm1f(x);
                cs[i][j] = 2.0f * (1.0f + u) / (u * (2.0f + u));
            }
            *(float4*)&ATTN[(rowbase + q0 + qg*4 + i) * SEQ + k0 + kg*4] =
                make_float4(cs[i][0], cs[i][1], cs[i][2], cs[i][3]);
            rsum[i] += cs[i][0] + cs[i][1] + cs[i][2] + cs[i][3];
        }

        __syncthreads();     // all K reads done; reuse KC as Cs[k][q]
#pragma unroll
        for (int j = 0; j < 4; ++j)
            *(float4*)&KC[kg*4 + j][qg*4] = make_float4(cs[0][j], cs[1][j], cs[2][j], cs[3][j]);
        __syncthreads();

        // PV: av[i][j] += sum_kk Cs[kk][qg*4+i] * Vs[kk][kg*4+j]
#pragma unroll 8
        for (int kk = 0; kk < 64; ++kk) {
            float4 cv = *(const float4*)&KC[kk][qg*4];
            float4 vv = *(const float4*)&Vs[kk][kg*4];
            float ca[4] = {cv.x, cv.y, cv.z, cv.w};
            float va[4] = {vv.x, vv.y, vv.z, vv.w};
#pragma unroll
            for (int i = 0; i < 4; ++i)
#pragma unroll
                for (int j = 0; j < 4; ++j)
                    av[i][j] = fmaf(ca[i], va[j], av[i][j]);
        }
    }

    // rowsum reduction across kg groups
#pragma unroll
    for (int m = 16; m < 64; m <<= 1)
#pragma unroll
        for (int i = 0; i < 4; ++i) rsum[i] += __shfl_xor(rsum[i], m);
    if ((tid & 63) < 16)
        *(float4*)&rs_part[w][qg*4] = make_float4(rsum[0], rsum[1], rsum[2], rsum[3]);
    __syncthreads();
    if (tid < 64)
        RS[rowbase + q0 + tid] = rs_part[0][tid] + rs_part[1][tid] + rs_part[2][tid] + rs_part[3][tid];

    // OV write (unnormalized)
#pragma unroll
    for (int i = 0; i < 4; ++i)
        *(float4*)&OV[(rowbase + q0 + qg*4 + i) * DEPTH + kg*4] =
            make_float4(av[i][0], av[i][1], av[i][2], av[i][3]);
}

// ---------------------------------------------------------------------------
// Normalize attn in place
// ---------------------------------------------------------------------------
__global__ __launch_bounds__(256) void attn_norm_kernel(
    float* __restrict__ ATTN, const float* __restrict__ RS)
{
    size_t i = (size_t)blockIdx.x * 256 + threadIdx.x;   // float4 index
    float inv = 1.0f / RS[i >> 9];
    float4* p = (float4*)ATTN;
    float4 v = p[i];
    v.x *= inv; v.y *= inv; v.z *= inv; v.w *= inv;
    p[i] = v;
}

// ---------------------------------------------------------------------------
// OV (BHSD, unnorm) -> normalized, (B*S,DM) layout, split to bf16 hi/lo
// ---------------------------------------------------------------------------
__global__ __launch_bounds__(256) void finalize_split_kernel(
    const float* __restrict__ OV, const float* __restrict__ RS,
    u16* __restrict__ H, u16* __restrict__ L)
{
    int i = blockIdx.x * 256 + threadIdx.x;   // float4 index
    int flat = i * 4;
    int bh  = flat >> 17;
    int rem = flat & (SEQ*DEPTH - 1);
    int s   = rem >> 6;
    int d   = rem & (DEPTH - 1);
    float inv = 1.0f / RS[bh * SEQ + s];
    float4 v = ((const float4*)OV)[i];
    v.x *= inv; v.y *= inv; v.z *= inv; v.w *= inv;
    int b = bh >> 4, h = bh & (NH - 1);
    size_t o = ((size_t)(b * SEQ + s)) * DM + h * DEPTH + d;
    u16 h0 = f2bf(v.x), h1 = f2bf(v.y), h2 = f2bf(v.z), h3 = f2bf(v.w);
    u16 l0 = f2bf(v.x - bf2f(h0)), l1 = f2bf(v.y - bf2f(h1));
    u16 l2 = f2bf(v.z - bf2f(h2)), l3 = f2bf(v.w - bf2f(h3));
    uint2 hh, ll;
    hh.x = (unsigned)h0 | ((unsigned)h1 << 16); hh.y = (unsigned)h2 | ((unsigned)h3 << 16);
    ll.x = (unsigned)l0 | ((unsigned)l1 << 16); ll.y = (unsigned)l2 | ((unsigned)l3 << 16);
    *(uint2*)&H[o] = hh;
    *(uint2*)&L[o] = ll;
}

// ---------------------------------------------------------------------------
extern "C" void kernel_launch(void* const* d_in, const int* in_sizes, int n_in,
                              void* d_out, int out_size, void* d_ws, size_t ws_size,
                              hipStream_t stream)
{
    const float* q_in = (const float*)d_in[0];
    const float* k_in = (const float*)d_in[1];
    const float* Wq = (const float*)d_in[2];
    const float* bq = (const float*)d_in[3];
    const float* Wk = (const float*)d_in[4];
    const float* bk = (const float*)d_in[5];
    const float* Wv = (const float*)d_in[6];
    const float* bvp = (const float*)d_in[7];
    const float* Wo = (const float*)d_in[8];
    const float* bo = (const float*)d_in[9];
    const float* g1 = (const float*)d_in[10];
    const float* b1 = (const float*)d_in[11];
    const float* g2 = (const float*)d_in[12];
    const float* b2 = (const float*)d_in[13];
    const float* g3 = (const float*)d_in[14];
    const float* b3 = (const float*)d_in[15];

    float* out0 = (float*)d_out;                     // (B,S,DM)
    float* attn = out0 + (size_t)ROWS * DM;          // (B,H,S,S)

    char* base = (char*)d_ws;
    const size_t SLOT = (size_t)ROWS * DM * 4;       // 16 MB
    float* S0f = (float*)(base);
    float* S1f = (float*)(base + SLOT);
    float* S2f = (float*)(base + 2*SLOT);
    float* S3f = (float*)(base + 3*SLOT);
    // split views (each slot = hi[4M] + lo[4M] u16)
    u16* S0h = (u16*)S0f; u16* S0l = S0h + (size_t)ROWS*DM;
    u16* S1h = (u16*)S1f; u16* S1l = S1h + (size_t)ROWS*DM;
    u16* S2h = (u16*)S2f; u16* S2l = S2h + (size_t)ROWS*DM;
    char* wbase = base + 4*SLOT;
    const size_t WSZ = (size_t)DM * DM * 2;          // 2 MB per bf16 matrix
    u16* WqH = (u16*)(wbase);           u16* WqL = (u16*)(wbase + WSZ);
    u16* WkH = (u16*)(wbase + 2*WSZ);   u16* WkL = (u16*)(wbase + 3*WSZ);
    u16* WvH = (u16*)(wbase + 4*WSZ);   u16* WvL = (u16*)(wbase + 5*WSZ);
    u16* WoH = (u16*)(wbase + 6*WSZ);   u16* WoL = (u16*)(wbase + 7*WSZ);
    float* ent = (float*)(wbase + 8*WSZ);
    float* rs  = ent + BHS;

    const dim3 wgrid(32, 32);
    const dim3 ggrid(DM/64, ROWS/128);               // (16, 32)

    // weight transpose+split
    wsplit_kernel<<<wgrid, 256, 0, stream>>>(Wq, WqH, WqL);
    wsplit_kernel<<<wgrid, 256, 0, stream>>>(Wk, WkH, WkL);
    wsplit_kernel<<<wgrid, 256, 0, stream>>>(Wv, WvH, WvL);
    wsplit_kernel<<<wgrid, 256, 0, stream>>>(Wo, WoH, WoL);

    // q chain: q1 = q_in@Wq+bq (split), q2 = q1@Wq+bq (fp32)
    split_kernel<<<ROWS*DM/(4*256), 256, 0, stream>>>(q_in, S0h, S0l);
    gemm_mfma<1><<<ggrid, 256, 0, stream>>>(S0h, S0l, WqH, WqL, bq, nullptr, S1h, S1l);
    gemm_mfma<0><<<ggrid, 256, 0, stream>>>(S1h, S1l, WqH, WqL, bq, S0f, nullptr, nullptr);
    // k chain: k1 = k_in@Wk+bk (split), k2 = k1@Wk+bk (fp32), v1 = k1@Wv+bv (fp32)
    split_kernel<<<ROWS*DM/(4*256), 256, 0, stream>>>(k_in, S1h, S1l);
    gemm_mfma<1><<<ggrid, 256, 0, stream>>>(S1h, S1l, WkH, WkL, bk, nullptr, S2h, S2l);
    gemm_mfma<0><<<ggrid, 256, 0, stream>>>(S2h, S2l, WkH, WkL, bk, S1f, nullptr, nullptr);
    gemm_mfma<0><<<ggrid, 256, 0, stream>>>(S2h, S2l, WvH, WvL, bvp, S3f, nullptr, nullptr);

    // LN + head softmax (BHSD outputs)
    ln_head_kernel<0><<<ROWS, 256, 0, stream>>>(S0f, g1, b1, S2f, ent);      // q_prob -> S2
    ln_head_kernel<1><<<ROWS, 256, 0, stream>>>(S1f, g2, b2, S0f, nullptr);  // logk   -> S0
    ln_head_kernel<2><<<ROWS, 256, 0, stream>>>(S3f, g3, b3, S1f, nullptr);  // v      -> S1

    // attention core
    attn2_kernel<<<dim3(SEQ/64, BS*NH), 256, 0, stream>>>(S2f, S0f, S1f, ent, attn, rs, S3f);
    attn_norm_kernel<<<(BS*NH*(size_t)SEQ*SEQ)/(4*256), 256, 0, stream>>>(attn, rs);

    // normalized out rows -> split, then final projection
    finalize_split_kernel<<<ROWS*DM/(4*256), 256, 0, stream>>>(S3f, rs, S0h, S0l);
    gemm_mfma<0><<<ggrid, 256, 0, stream>>>(S0h, S0l, WoH, WoL, bo, out0, nullptr, nullptr);
}

// Round 3
// 769.756 us; speedup vs baseline: 2.1924x; 1.4007x over previous
//
#include <hip/hip_runtime.h>
#include <cstddef>
#include <cstdint>

#define BS      2
#define SEQ     2048
#define DM      1024
#define NH      16
#define DEPTH   64
#define ROWS    (BS*SEQ)          // 4096
#define BHS     (BS*NH*SEQ)       // 65536

typedef unsigned short u16;
typedef __attribute__((ext_vector_type(8))) short short8v;
typedef __attribute__((ext_vector_type(4))) float f32x4;

__device__ __forceinline__ u16 f2bf(float x) {
    unsigned u = __builtin_bit_cast(unsigned, x);
    unsigned r = u + 0x7FFFu + ((u >> 16) & 1u);
    return (u16)(r >> 16);
}
__device__ __forceinline__ float bf2f(u16 h) {
    unsigned u = ((unsigned)h) << 16;
    return __builtin_bit_cast(float, u);
}

// ---------------------------------------------------------------------------
// Weight transpose + split: W[K][N] fp32 -> Wt hi/lo [N][K] bf16
// ---------------------------------------------------------------------------
__global__ __launch_bounds__(256) void wsplit_kernel(
    const float* __restrict__ W, u16* __restrict__ H, u16* __restrict__ L)
{
    __shared__ float tile[32][33];
    const int bn = blockIdx.x, bk = blockIdx.y;
    const int c = threadIdx.x & 31, r0 = threadIdx.x >> 5;
#pragma unroll
    for (int r = 0; r < 32; r += 8)
        tile[r0 + r][c] = W[(size_t)(bk*32 + r0 + r) * DM + bn*32 + c];
    __syncthreads();
#pragma unroll
    for (int r = 0; r < 32; r += 8) {
        float v = tile[c][r0 + r];
        u16 h = f2bf(v);
        size_t o = (size_t)(bn*32 + r0 + r) * DM + bk*32 + c;
        H[o] = h;
        L[o] = f2bf(v - bf2f(h));
    }
}

// ---------------------------------------------------------------------------
// Elementwise split fp32 -> bf16 hi/lo
// ---------------------------------------------------------------------------
__global__ __launch_bounds__(256) void split_kernel(
    const float* __restrict__ X, u16* __restrict__ H, u16* __restrict__ L)
{
    int i = blockIdx.x * 256 + threadIdx.x;        // float4 index
    float4 v = ((const float4*)X)[i];
    u16 h0 = f2bf(v.x), h1 = f2bf(v.y), h2 = f2bf(v.z), h3 = f2bf(v.w);
    u16 l0 = f2bf(v.x - bf2f(h0)), l1 = f2bf(v.y - bf2f(h1));
    u16 l2 = f2bf(v.z - bf2f(h2)), l3 = f2bf(v.w - bf2f(h3));
    uint2 hh, ll;
    hh.x = (unsigned)h0 | ((unsigned)h1 << 16); hh.y = (unsigned)h2 | ((unsigned)h3 << 16);
    ll.x = (unsigned)l0 | ((unsigned)l1 << 16); ll.y = (unsigned)l2 | ((unsigned)l3 << 16);
    ((uint2*)H)[i] = hh;
    ((uint2*)L)[i] = ll;
}

// ---------------------------------------------------------------------------
// Split-bf16 MFMA GEMM (unchanged from r2): C = A@W + bias
// ---------------------------------------------------------------------------
template<int OUT_MODE>
__global__ __launch_bounds__(256) void gemm_mfma(
    const u16* __restrict__ Ah, const u16* __restrict__ Al,
    const u16* __restrict__ Bh, const u16* __restrict__ Bl,
    const float* __restrict__ bias, float* __restrict__ C,
    u16* __restrict__ Ch, u16* __restrict__ Cl)
{
    constexpr int K = 1024, N = 1024;
    __shared__ u16 AsH[128*40], AsL[128*40], BsH[64*40], BsL[64*40];

    const int t = threadIdx.x;
    const int m0 = blockIdx.y * 128;
    const int n0 = blockIdx.x * 64;
    const int lane = t & 63, w = t >> 6;
    const int wr = w >> 1, wc = w & 1;
    const int lr = lane & 15, lk = lane >> 4;

    f32x4 acc[4][2];
#pragma unroll
    for (int i = 0; i < 4; ++i)
#pragma unroll
        for (int j = 0; j < 2; ++j) acc[i][j] = (f32x4){0.f,0.f,0.f,0.f};

    for (int k0 = 0; k0 < K; k0 += 32) {
        __syncthreads();
#pragma unroll
        for (int r = 0; r < 2; ++r) {
            int s = r*256 + t;
            int row = s >> 2, c = s & 3;
            size_t g = (size_t)(m0 + row) * K + k0 + c*8;
            *(short8v*)&AsH[row*40 + c*8] = *(const short8v*)&Ah[g];
            *(short8v*)&AsL[row*40 + c*8] = *(const short8v*)&Al[g];
        }
        {
            int row = t >> 2, c = t & 3;
            size_t g = (size_t)(n0 + row) * K + k0 + c*8;
            *(short8v*)&BsH[row*40 + c*8] = *(const short8v*)&Bh[g];
            *(short8v*)&BsL[row*40 + c*8] = *(const short8v*)&Bl[g];
        }
        __syncthreads();

        short8v ah[4], al[4], bh[2], bl[2];
#pragma unroll
        for (int i = 0; i < 4; ++i) {
            int off = (wr*64 + i*16 + lr)*40 + lk*8;
            ah[i] = *(const short8v*)&AsH[off];
            al[i] = *(const short8v*)&AsL[off];
        }
#pragma unroll
        for (int j = 0; j < 2; ++j) {
            int off = (wc*32 + j*16 + lr)*40 + lk*8;
            bh[j] = *(const short8v*)&BsH[off];
            bl[j] = *(const short8v*)&BsL[off];
        }
#pragma unroll
        for (int i = 0; i < 4; ++i)
#pragma unroll
            for (int j = 0; j < 2; ++j) {
                acc[i][j] = __builtin_amdgcn_mfma_f32_16x16x32_bf16(ah[i], bh[j], acc[i][j], 0, 0, 0);
                acc[i][j] = __builtin_amdgcn_mfma_f32_16x16x32_bf16(ah[i], bl[j], acc[i][j], 0, 0, 0);
                acc[i][j] = __builtin_amdgcn_mfma_f32_16x16x32_bf16(al[i], bh[j], acc[i][j], 0, 0, 0);
            }
    }

    float bj[2];
#pragma unroll
    for (int j = 0; j < 2; ++j) bj[j] = bias[n0 + wc*32 + j*16 + lr];
#pragma unroll
    for (int i = 0; i < 4; ++i)
#pragma unroll
        for (int j = 0; j < 2; ++j) {
            int col = n0 + wc*32 + j*16 + lr;
#pragma unroll
            for (int r = 0; r < 4; ++r) {
                int row = m0 + wr*64 + i*16 + lk*4 + r;
                float v = acc[i][j][r] + bj[j];
                size_t o = (size_t)row * N + col;
                if constexpr (OUT_MODE == 0) {
                    C[o] = v;
                } else {
                    u16 h = f2bf(v);
                    Ch[o] = h;
                    Cl[o] = f2bf(v - bf2f(h));
                }
            }
        }
}

// ---------------------------------------------------------------------------
// Fused LayerNorm -> per-head softmax; bf16 outputs in BHSD layout.
// MODE 0: OA/OB = q_prob hi/lo + ENT ; MODE 1: OA/OB = log(prob+eps) hi/lo ;
// MODE 2: OA = LN result bf16 (single).
// ---------------------------------------------------------------------------
template<int MODE>
__global__ __launch_bounds__(256) void ln_head_kernel(
    const float* __restrict__ X, const float* __restrict__ G,
    const float* __restrict__ Bt, u16* __restrict__ OA,
    u16* __restrict__ OB, float* __restrict__ ENT)
{
    const int row = blockIdx.x;
    const int tid = threadIdx.x;
    const float* x = X + (size_t)row * DM;
    float4 v = *(const float4*)&x[tid*4];

    float s  = v.x + v.y + v.z + v.w;
    float ss = v.x*v.x + v.y*v.y + v.z*v.z + v.w*v.w;
#pragma unroll
    for (int m = 1; m < 64; m <<= 1) { s += __shfl_xor(s, m); ss += __shfl_xor(ss, m); }
    __shared__ float redS[4], redQ[4];
    const int wave = tid >> 6, lane = tid & 63;
    if (lane == 0) { redS[wave] = s; redQ[wave] = ss; }
    __syncthreads();
    s  = redS[0] + redS[1] + redS[2] + redS[3];
    ss = redQ[0] + redQ[1] + redQ[2] + redQ[3];
    const float mu   = s * (1.0f / DM);
    const float var  = ss * (1.0f / DM) - mu * mu;
    const float rsig = rsqrtf(var + 1e-6f);

    float4 gv = *(const float4*)&G[tid*4];
    float4 bv = *(const float4*)&Bt[tid*4];
    float y0 = (v.x - mu) * rsig * gv.x + bv.x;
    float y1 = (v.y - mu) * rsig * gv.y + bv.y;
    float y2 = (v.z - mu) * rsig * gv.z + bv.z;
    float y3 = (v.w - mu) * rsig * gv.w + bv.w;

    const int b  = row >> 11;
    const int sl = row & (SEQ - 1);
    const int h  = tid >> 4;
    const size_t obase = (((size_t)(b*NH + h)) * SEQ + sl) * DEPTH + (tid & 15) * 4;

    if constexpr (MODE == 2) {
        unsigned w0 = (unsigned)f2bf(y0) | ((unsigned)f2bf(y1) << 16);
        unsigned w1 = (unsigned)f2bf(y2) | ((unsigned)f2bf(y3) << 16);
        *(uint2*)&OA[obase] = make_uint2(w0, w1);
    } else {
        float mx = fmaxf(fmaxf(y0, y1), fmaxf(y2, y3));
#pragma unroll
        for (int m = 1; m < 16; m <<= 1) mx = fmaxf(mx, __shfl_xor(mx, m, 16));
        float e0 = expf(y0 - mx), e1 = expf(y1 - mx), e2 = expf(y2 - mx), e3 = expf(y3 - mx);
        float se = e0 + e1 + e2 + e3;
#pragma unroll
        for (int m = 1; m < 16; m <<= 1) se += __shfl_xor(se, m, 16);
        float inv = 1.0f / se;
        float p0 = e0*inv, p1 = e1*inv, p2 = e2*inv, p3 = e3*inv;
        float o0, o1, o2, o3;
        if constexpr (MODE == 0) { o0 = p0; o1 = p1; o2 = p2; o3 = p3; }
        else {
            o0 = logf(p0 + 2e-8f); o1 = logf(p1 + 2e-8f);
            o2 = logf(p2 + 2e-8f); o3 = logf(p3 + 2e-8f);
        }
        u16 h0 = f2bf(o0), h1 = f2bf(o1), h2 = f2bf(o2), h3 = f2bf(o3);
        unsigned w0 = (unsigned)h0 | ((unsigned)h1 << 16);
        unsigned w1 = (unsigned)h2 | ((unsigned)h3 << 16);
        *(uint2*)&OA[obase] = make_uint2(w0, w1);
        u16 l0 = f2bf(o0 - bf2f(h0)), l1 = f2bf(o1 - bf2f(h1));
        u16 l2 = f2bf(o2 - bf2f(h2)), l3 = f2bf(o3 - bf2f(h3));
        w0 = (unsigned)l0 | ((unsigned)l1 << 16);
        w1 = (unsigned)l2 | ((unsigned)l3 << 16);
        *(uint2*)&OB[obase] = make_uint2(w0, w1);

        if constexpr (MODE == 0) {
            float lse = logf(se);
            float el = p0*(y0-mx-lse) + p1*(y1-mx-lse) + p2*(y2-mx-lse) + p3*(y3-mx-lse);
#pragma unroll
            for (int m = 1; m < 16; m <<= 1) el += __shfl_xor(el, m, 16);
            if ((tid & 15) == 0) ENT[((size_t)(b*NH + h)) * SEQ + sl] = el;
        }
    }
}

// ---------------------------------------------------------------------------
// V transpose: Vb [bh][s][d] bf16 -> VT [bh][d][s] bf16
// ---------------------------------------------------------------------------
__global__ __launch_bounds__(256) void vtrans_kernel(
    const u16* __restrict__ Vb, u16* __restrict__ VT)
{
    size_t i = (size_t)blockIdx.x * 256 + threadIdx.x;  // slots of 8 u16
    int bh  = (int)(i >> 14);
    int rem = (int)(i & 16383);
    int s   = rem >> 3;
    int d0  = (rem & 7) * 8;
    short8v v = *(const short8v*)&Vb[(((size_t)bh * SEQ) + s) * DEPTH + d0];
#pragma unroll
    for (int j = 0; j < 8; ++j)
        VT[((size_t)bh * DEPTH + d0 + j) * SEQ + s] = (u16)v[j];
}

// ---------------------------------------------------------------------------
// attn3: MFMA attention, two-phase (A: rowsums; B: normalized write + PV).
// Block: 64 q rows, 4 waves (wave = 16q x 64k frags), k chunks of 64.
// QK: split-bf16 (3 MFMA); PV: single bf16. Writes normalized ATTN and
// normalized OV (split bf16, (B,S,DM) layout) directly.
// ---------------------------------------------------------------------------
__global__ __launch_bounds__(256) void attn3_kernel(
    const u16* __restrict__ QPh, const u16* __restrict__ QPl,
    const u16* __restrict__ LKh, const u16* __restrict__ LKl,
    const u16* __restrict__ VT, const float* __restrict__ ENT,
    float* __restrict__ ATTN, u16* __restrict__ OH, u16* __restrict__ OL)
{
    const int bh = blockIdx.y;
    const int q0 = blockIdx.x * 64;
    const int t  = threadIdx.x;
    const int l  = t & 63, w = t >> 6;
    const int lr = l & 15, lg = l >> 4;
    const size_t rbase = (size_t)bh * SEQ;

    __shared__ u16 QhS[64*72], QlS[64*72];
    __shared__ u16 KhS[64*72], KlS[64*72];
    __shared__ u16 VtS[64*72];           // [d][k]
    __shared__ u16 PS[64*72];            // normalized attn bf16 [q][k]
    __shared__ float entS[64];

    // stage Q (once)
#pragma unroll
    for (int r = 0; r < 2; ++r) {
        int s = r*256 + t; int q = s >> 3, d0 = (s & 7) * 8;
        size_t g = (rbase + q0 + q) * DEPTH + d0;
        *(short8v*)&QhS[q*72 + d0] = *(const short8v*)&QPh[g];
        *(short8v*)&QlS[q*72 + d0] = *(const short8v*)&QPl[g];
    }
    if (t < 64) entS[t] = ENT[rbase + q0 + t];
    __syncthreads();
    float e[4];
#pragma unroll
    for (int r = 0; r < 4; ++r) e[r] = entS[w*16 + lg*4 + r];

    // ---------------- phase A: rowsums ----------------
    float rs[4] = {0.f, 0.f, 0.f, 0.f};
    for (int k0 = 0; k0 < SEQ; k0 += 64) {
        if (k0) __syncthreads();
#pragma unroll
        for (int r = 0; r < 2; ++r) {
            int s = r*256 + t; int kr = s >> 3, d0 = (s & 7) * 8;
            size_t g = (rbase + k0 + kr) * DEPTH + d0;
            *(short8v*)&KhS[kr*72 + d0] = *(const short8v*)&LKh[g];
            *(short8v*)&KlS[kr*72 + d0] = *(const short8v*)&LKl[g];
        }
        __syncthreads();

        short8v qh[2], ql[2];
#pragma unroll
        for (int d = 0; d < 2; ++d) {
            int off = (w*16 + lr)*72 + d*32 + lg*8;
            qh[d] = *(const short8v*)&QhS[off];
            ql[d] = *(const short8v*)&QlS[off];
        }
        f32x4 acc[4];
#pragma unroll
        for (int f = 0; f < 4; ++f) acc[f] = (f32x4){0.f,0.f,0.f,0.f};
#pragma unroll
        for (int f = 0; f < 4; ++f)
#pragma unroll
            for (int d = 0; d < 2; ++d) {
                int off = (f*16 + lr)*72 + d*32 + lg*8;
                short8v kbh = *(const short8v*)&KhS[off];
                short8v kbl = *(const short8v*)&KlS[off];
                acc[f] = __builtin_amdgcn_mfma_f32_16x16x32_bf16(qh[d], kbh, acc[f], 0, 0, 0);
                acc[f] = __builtin_amdgcn_mfma_f32_16x16x32_bf16(qh[d], kbl, acc[f], 0, 0, 0);
                acc[f] = __builtin_amdgcn_mfma_f32_16x16x32_bf16(ql[d], kbh, acc[f], 0, 0, 0);
            }
#pragma unroll
        for (int f = 0; f < 4; ++f)
#pragma unroll
            for (int r = 0; r < 4; ++r) {
                float x = (e[r] - acc[f][r]) * 0.125f;
                float u = expm1f(x);
                rs[r] += 2.0f * (1.0f + u) / (u * (2.0f + u));
            }
    }
#pragma unroll
    for (int m = 1; m < 16; m <<= 1)
#pragma unroll
        for (int r = 0; r < 4; ++r) rs[r] += __shfl_xor(rs[r], m, 16);
    float inv[4];
#pragma unroll
    for (int r = 0; r < 4; ++r) inv[r] = 1.0f / rs[r];

    // ---------------- phase B: write + PV ----------------
    f32x4 av[4];
#pragma unroll
    for (int nf = 0; nf < 4; ++nf) av[nf] = (f32x4){0.f,0.f,0.f,0.f};

    for (int k0 = 0; k0 < SEQ; k0 += 64) {
        __syncthreads();
#pragma unroll
        for (int r = 0; r < 2; ++r) {
            int s = r*256 + t; int kr = s >> 3, d0 = (s & 7) * 8;
            size_t g = (rbase + k0 + kr) * DEPTH + d0;
            *(short8v*)&KhS[kr*72 + d0] = *(const short8v*)&LKh[g];
            *(short8v*)&KlS[kr*72 + d0] = *(const short8v*)&LKl[g];
        }
#pragma unroll
        for (int r = 0; r < 2; ++r) {
            int s = r*256 + t; int dd = s >> 3, kk0 = (s & 7) * 8;
            *(short8v*)&VtS[dd*72 + kk0] =
                *(const short8v*)&VT[((size_t)bh * DEPTH + dd) * SEQ + k0 + kk0];
        }
        __syncthreads();

        short8v qh[2], ql[2];
#pragma unroll
        for (int d = 0; d < 2; ++d) {
            int off = (w*16 + lr)*72 + d*32 + lg*8;
            qh[d] = *(const short8v*)&QhS[off];
            ql[d] = *(const short8v*)&QlS[off];
        }
        f32x4 acc[4];
#pragma unroll
        for (int f = 0; f < 4; ++f) acc[f] = (f32x4){0.f,0.f,0.f,0.f};
#pragma unroll
        for (int f = 0; f < 4; ++f)
#pragma unroll
            for (int d = 0; d < 2; ++d) {
                int off = (f*16 + lr)*72 + d*32 + lg*8;
                short8v kbh = *(const short8v*)&KhS[off];
                short8v kbl = *(const short8v*)&KlS[off];
                acc[f] = __builtin_amdgcn_mfma_f32_16x16x32_bf16(qh[d], kbh, acc[f], 0, 0, 0);
                acc[f] = __builtin_amdgcn_mfma_f32_16x16x32_bf16(qh[d], kbl, acc[f], 0, 0, 0);
                acc[f] = __builtin_amdgcn_mfma_f32_16x16x32_bf16(ql[d], kbh, acc[f], 0, 0, 0);
            }
#pragma unroll
        for (int f = 0; f < 4; ++f)
#pragma unroll
            for (int r = 0; r < 4; ++r) {
                float x = (e[r] - acc[f][r]) * 0.125f;
                float u = expm1f(x);
                float a = 2.0f * (1.0f + u) / (u * (2.0f + u)) * inv[r];
                int q = w*16 + lg*4 + r;
                ATTN[(rbase + q0 + q) * SEQ + k0 + f*16 + lr] = a;
                PS[q*72 + f*16 + lr] = f2bf(a);
            }
        __syncthreads();

        short8v pa[2];
#pragma unroll
        for (int ks = 0; ks < 2; ++ks)
            pa[ks] = *(const short8v*)&PS[(w*16 + lr)*72 + ks*32 + lg*8];
#pragma unroll
        for (int nf = 0; nf < 4; ++nf)
#pragma unroll
            for (int ks = 0; ks < 2; ++ks) {
                short8v vb = *(const short8v*)&VtS[(nf*16 + lr)*72 + ks*32 + lg*8];
                av[nf] = __builtin_amdgcn_mfma_f32_16x16x32_bf16(pa[ks], vb, av[nf], 0, 0, 0);
            }
    }

    // OV write: normalized, (B,S,DM) layout, split bf16
    const int b = bh >> 4, h = bh & (NH - 1);
#pragma unroll
    for (int nf = 0; nf < 4; ++nf)
#pragma unroll
        for (int r = 0; r < 4; ++r) {
            int q = w*16 + lg*4 + r;
            int d = nf*16 + lr;
            size_t o = ((size_t)(b * SEQ + q0 + q)) * DM + h * DEPTH + d;
            float v = av[nf][r];
            u16 hh = f2bf(v);
            OH[o] = hh;
            OL[o] = f2bf(v - bf2f(hh));
        }
}

// ---------------------------------------------------------------------------
extern "C" void kernel_launch(void* const* d_in, const int* in_sizes, int n_in,
                              void* d_out, int out_size, void* d_ws, size_t ws_size,
                              hipStream_t stream)
{
    const float* q_in = (const float*)d_in[0];
    const float* k_in = (const float*)d_in[1];
    const float* Wq = (const float*)d_in[2];
    const float* bq = (const float*)d_in[3];
    const float* Wk = (const float*)d_in[4];
    const float* bk = (const float*)d_in[5];
    const float* Wv = (const float*)d_in[6];
    const float* bvp = (const float*)d_in[7];
    const float* Wo = (const float*)d_in[8];
    const float* bo = (const float*)d_in[9];
    const float* g1 = (const float*)d_in[10];
    const float* b1 = (const float*)d_in[11];
    const float* g2 = (const float*)d_in[12];
    const float* b2 = (const float*)d_in[13];
    const float* g3 = (const float*)d_in[14];
    const float* b3 = (const float*)d_in[15];

    float* out0 = (float*)d_out;                     // (B,S,DM)
    float* attn = out0 + (size_t)ROWS * DM;          // (B,H,S,S)

    char* base = (char*)d_ws;
    const size_t SLOT = (size_t)ROWS * DM * 4;       // 16 MB
    const size_t HALF = (size_t)ROWS * DM;           // 4M elements (u16 half-slot)
    float* S0f = (float*)(base);
    float* S1f = (float*)(base + SLOT);
    float* S2f = (float*)(base + 2*SLOT);
    float* S3f = (float*)(base + 3*SLOT);
    u16* S0h = (u16*)S0f; u16* S0l = S0h + HALF;
    u16* S1h = (u16*)S1f; u16* S1l = S1h + HALF;
    u16* S3h = (u16*)S3f; u16* S3l = S3h + HALF;
    // attention operand views
    u16* QPh = (u16*)S3f; u16* QPl = QPh + HALF;
    u16* LKh = (u16*)S2f; u16* LKl = LKh + HALF;
    u16* Vb  = (u16*)S0f; u16* VTp = Vb + HALF;
    u16* OHp = (u16*)S1f; u16* OLp = OHp + HALF;

    char* wbase = base + 4*SLOT;
    const size_t WSZ = (size_t)DM * DM * 2;          // 2 MB per bf16 matrix
    u16* WqH = (u16*)(wbase);           u16* WqL = (u16*)(wbase + WSZ);
    u16* WkH = (u16*)(wbase + 2*WSZ);   u16* WkL = (u16*)(wbase + 3*WSZ);
    u16* WvH = (u16*)(wbase + 4*WSZ);   u16* WvL = (u16*)(wbase + 5*WSZ);
    u16* WoH = (u16*)(wbase + 6*WSZ);   u16* WoL = (u16*)(wbase + 7*WSZ);
    float* ent = (float*)(wbase + 8*WSZ);

    const dim3 wgrid(32, 32);
    const dim3 ggrid(DM/64, ROWS/128);               // (16, 32)

    wsplit_kernel<<<wgrid, 256, 0, stream>>>(Wq, WqH, WqL);
    wsplit_kernel<<<wgrid, 256, 0, stream>>>(Wk, WkH, WkL);
    wsplit_kernel<<<wgrid, 256, 0, stream>>>(Wv, WvH, WvL);
    wsplit_kernel<<<wgrid, 256, 0, stream>>>(Wo, WoH, WoL);

    // q chain: q1 = q_in@Wq+bq (split, ->S1), q2 = q1@Wq+bq (fp32 ->S2)
    split_kernel<<<ROWS*DM/(4*256), 256, 0, stream>>>(q_in, S0h, S0l);
    gemm_mfma<1><<<ggrid, 256, 0, stream>>>(S0h, S0l, WqH, WqL, bq, nullptr, S1h, S1l);
    gemm_mfma<0><<<ggrid, 256, 0, stream>>>(S1h, S1l, WqH, WqL, bq, S2f, nullptr, nullptr);
    // k chain: k1 (split ->S3), k2 (fp32 ->S0), v1 (fp32 ->S1)
    split_kernel<<<ROWS*DM/(4*256), 256, 0, stream>>>(k_in, S0h, S0l);
    gemm_mfma<1><<<ggrid, 256, 0, stream>>>(S0h, S0l, WkH, WkL, bk, nullptr, S3h, S3l);
    gemm_mfma<0><<<ggrid, 256, 0, stream>>>(S3h, S3l, WkH, WkL, bk, S0f, nullptr, nullptr);
    gemm_mfma<0><<<ggrid, 256, 0, stream>>>(S3h, S3l, WvH, WvL, bvp, S1f, nullptr, nullptr);

    // LN + head softmax -> bf16 BHSD operands
    ln_head_kernel<0><<<ROWS, 256, 0, stream>>>(S2f, g1, b1, QPh, QPl, ent);
    ln_head_kernel<1><<<ROWS, 256, 0, stream>>>(S0f, g2, b2, LKh, LKl, nullptr);
    ln_head_kernel<2><<<ROWS, 256, 0, stream>>>(S1f, g3, b3, Vb, nullptr, nullptr);
    vtrans_kernel<<<BHS*8/256, 256, 0, stream>>>(Vb, VTp);

    // fused attention (normalized attn + normalized split OV)
    attn3_kernel<<<dim3(SEQ/64, BS*NH), 256, 0, stream>>>(
        QPh, QPl, LKh, LKl, VTp, ent, attn, OHp, OLp);

    // final projection
    gemm_mfma<0><<<ggrid, 256, 0, stream>>>(OHp, OLp, WoH, WoL, bo, out0, nullptr, nullptr);
}

// Round 4
// 621.677 us; speedup vs baseline: 2.7146x; 1.2382x over previous
//
#include <hip/hip_runtime.h>
#include <cstddef>
#include <cstdint>

#define BS      2
#define SEQ     2048
#define DM      1024
#define NH      16
#define DEPTH   64
#define ROWS    (BS*SEQ)          // 4096
#define BHS     (BS*NH*SEQ)       // 65536

typedef unsigned short u16;
typedef __attribute__((ext_vector_type(8))) short short8v;
typedef __attribute__((ext_vector_type(4))) float f32x4;

// swizzled byte offset into a [64 rows][128 B] LDS tile (T2 / G4 fix)
#define SWZ(row, cb) ((((row) << 7)) | ((cb) ^ (((row) & 7) << 4)))

__device__ __forceinline__ u16 f2bf(float x) {
    unsigned u = __builtin_bit_cast(unsigned, x);
    unsigned r = u + 0x7FFFu + ((u >> 16) & 1u);
    return (u16)(r >> 16);
}
__device__ __forceinline__ float bf2f(u16 h) {
    unsigned u = ((unsigned)h) << 16;
    return __builtin_bit_cast(float, u);
}

// fast csch(x) = 1/sinh(x): big path 2t/(t^2-1), t=e^x; small path 1/x - x/6.
__device__ __forceinline__ float fast_csch(float x) {
    float t   = __expf(x);
    float den = fmaf(t, t, -1.0f);
    float rd  = __builtin_amdgcn_rcpf(den);
    rd        = rd * fmaf(-den, rd, 2.0f);          // 1 Newton step
    float cbig = 2.0f * t * rd;
    float rx  = __builtin_amdgcn_rcpf(x);
    rx        = rx * fmaf(-x, rx, 2.0f);
    float csmall = fmaf(x, -(1.0f/6.0f), rx);
    return (fabsf(x) < 0.04f) ? csmall : cbig;
}

// ---------------------------------------------------------------------------
// Weight transpose + split: W[K][N] fp32 -> Wt hi/lo [N][K] bf16
// ---------------------------------------------------------------------------
__global__ __launch_bounds__(256) void wsplit_kernel(
    const float* __restrict__ W, u16* __restrict__ H, u16* __restrict__ L)
{
    __shared__ float tile[32][33];
    const int bn = blockIdx.x, bk = blockIdx.y;
    const int c = threadIdx.x & 31, r0 = threadIdx.x >> 5;
#pragma unroll
    for (int r = 0; r < 32; r += 8)
        tile[r0 + r][c] = W[(size_t)(bk*32 + r0 + r) * DM + bn*32 + c];
    __syncthreads();
#pragma unroll
    for (int r = 0; r < 32; r += 8) {
        float v = tile[c][r0 + r];
        u16 h = f2bf(v);
        size_t o = (size_t)(bn*32 + r0 + r) * DM + bk*32 + c;
        H[o] = h;
        L[o] = f2bf(v - bf2f(h));
    }
}

// ---------------------------------------------------------------------------
// Elementwise split fp32 -> bf16 hi/lo
// ---------------------------------------------------------------------------
__global__ __launch_bounds__(256) void split_kernel(
    const float* __restrict__ X, u16* __restrict__ H, u16* __restrict__ L)
{
    int i = blockIdx.x * 256 + threadIdx.x;        // float4 index
    float4 v = ((const float4*)X)[i];
    u16 h0 = f2bf(v.x), h1 = f2bf(v.y), h2 = f2bf(v.z), h3 = f2bf(v.w);
    u16 l0 = f2bf(v.x - bf2f(h0)), l1 = f2bf(v.y - bf2f(h1));
    u16 l2 = f2bf(v.z - bf2f(h2)), l3 = f2bf(v.w - bf2f(h3));
    uint2 hh, ll;
    hh.x = (unsigned)h0 | ((unsigned)h1 << 16); hh.y = (unsigned)h2 | ((unsigned)h3 << 16);
    ll.x = (unsigned)l0 | ((unsigned)l1 << 16); ll.y = (unsigned)l2 | ((unsigned)l3 << 16);
    ((uint2*)H)[i] = hh;
    ((uint2*)L)[i] = ll;
}

// ---------------------------------------------------------------------------
// Split-bf16 MFMA GEMM: C = A@W + bias
// ---------------------------------------------------------------------------
template<int OUT_MODE>
__global__ __launch_bounds__(256) void gemm_mfma(
    const u16* __restrict__ Ah, const u16* __restrict__ Al,
    const u16* __restrict__ Bh, const u16* __restrict__ Bl,
    const float* __restrict__ bias, float* __restrict__ C,
    u16* __restrict__ Ch, u16* __restrict__ Cl)
{
    constexpr int K = 1024, N = 1024;
    __shared__ u16 AsH[128*40], AsL[128*40], BsH[64*40], BsL[64*40];

    const int t = threadIdx.x;
    const int m0 = blockIdx.y * 128;
    const int n0 = blockIdx.x * 64;
    const int lane = t & 63, w = t >> 6;
    const int wr = w >> 1, wc = w & 1;
    const int lr = lane & 15, lk = lane >> 4;

    f32x4 acc[4][2];
#pragma unroll
    for (int i = 0; i < 4; ++i)
#pragma unroll
        for (int j = 0; j < 2; ++j) acc[i][j] = (f32x4){0.f,0.f,0.f,0.f};

    for (int k0 = 0; k0 < K; k0 += 32) {
        __syncthreads();
#pragma unroll
        for (int r = 0; r < 2; ++r) {
            int s = r*256 + t;
            int row = s >> 2, c = s & 3;
            size_t g = (size_t)(m0 + row) * K + k0 + c*8;
            *(short8v*)&AsH[row*40 + c*8] = *(const short8v*)&Ah[g];
            *(short8v*)&AsL[row*40 + c*8] = *(const short8v*)&Al[g];
        }
        {
            int row = t >> 2, c = t & 3;
            size_t g = (size_t)(n0 + row) * K + k0 + c*8;
            *(short8v*)&BsH[row*40 + c*8] = *(const short8v*)&Bh[g];
            *(short8v*)&BsL[row*40 + c*8] = *(const short8v*)&Bl[g];
        }
        __syncthreads();

        short8v ah[4], al[4], bh[2], bl[2];
#pragma unroll
        for (int i = 0; i < 4; ++i) {
            int off = (wr*64 + i*16 + lr)*40 + lk*8;
            ah[i] = *(const short8v*)&AsH[off];
            al[i] = *(const short8v*)&AsL[off];
        }
#pragma unroll
        for (int j = 0; j < 2; ++j) {
            int off = (wc*32 + j*16 + lr)*40 + lk*8;
            bh[j] = *(const short8v*)&BsH[off];
            bl[j] = *(const short8v*)&BsL[off];
        }
        __builtin_amdgcn_s_setprio(1);
#pragma unroll
        for (int i = 0; i < 4; ++i)
#pragma unroll
            for (int j = 0; j < 2; ++j) {
                acc[i][j] = __builtin_amdgcn_mfma_f32_16x16x32_bf16(ah[i], bh[j], acc[i][j], 0, 0, 0);
                acc[i][j] = __builtin_amdgcn_mfma_f32_16x16x32_bf16(ah[i], bl[j], acc[i][j], 0, 0, 0);
                acc[i][j] = __builtin_amdgcn_mfma_f32_16x16x32_bf16(al[i], bh[j], acc[i][j], 0, 0, 0);
            }
        __builtin_amdgcn_s_setprio(0);
    }

    float bj[2];
#pragma unroll
    for (int j = 0; j < 2; ++j) bj[j] = bias[n0 + wc*32 + j*16 + lr];
#pragma unroll
    for (int i = 0; i < 4; ++i)
#pragma unroll
        for (int j = 0; j < 2; ++j) {
            int col = n0 + wc*32 + j*16 + lr;
#pragma unroll
            for (int r = 0; r < 4; ++r) {
                int row = m0 + wr*64 + i*16 + lk*4 + r;
                float v = acc[i][j][r] + bj[j];
                size_t o = (size_t)row * N + col;
                if constexpr (OUT_MODE == 0) {
                    C[o] = v;
                } else {
                    u16 h = f2bf(v);
                    Ch[o] = h;
                    Cl[o] = f2bf(v - bf2f(h));
                }
            }
        }
}

// ---------------------------------------------------------------------------
// Fused LayerNorm -> per-head softmax; bf16 outputs in BHSD layout.
// MODE 0: OA/OB = q_prob hi/lo + ENT ; MODE 1: OA/OB = log(prob+eps) hi/lo ;
// MODE 2: OA = LN result bf16 (single).
// ---------------------------------------------------------------------------
template<int MODE>
__global__ __launch_bounds__(256) void ln_head_kernel(
    const float* __restrict__ X, const float* __restrict__ G,
    const float* __restrict__ Bt, u16* __restrict__ OA,
    u16* __restrict__ OB, float* __restrict__ ENT)
{
    const int row = blockIdx.x;
    const int tid = threadIdx.x;
    const float* x = X + (size_t)row * DM;
    float4 v = *(const float4*)&x[tid*4];

    float s  = v.x + v.y + v.z + v.w;
    float ss = v.x*v.x + v.y*v.y + v.z*v.z + v.w*v.w;
#pragma unroll
    for (int m = 1; m < 64; m <<= 1) { s += __shfl_xor(s, m); ss += __shfl_xor(ss, m); }
    __shared__ float redS[4], redQ[4];
    const int wave = tid >> 6, lane = tid & 63;
    if (lane == 0) { redS[wave] = s; redQ[wave] = ss; }
    __syncthreads();
    s  = redS[0] + redS[1] + redS[2] + redS[3];
    ss = redQ[0] + redQ[1] + redQ[2] + redQ[3];
    const float mu   = s * (1.0f / DM);
    const float var  = ss * (1.0f / DM) - mu * mu;
    const float rsig = rsqrtf(var + 1e-6f);

    float4 gv = *(const float4*)&G[tid*4];
    float4 bv = *(const float4*)&Bt[tid*4];
    float y0 = (v.x - mu) * rsig * gv.x + bv.x;
    float y1 = (v.y - mu) * rsig * gv.y + bv.y;
    float y2 = (v.z - mu) * rsig * gv.z + bv.z;
    float y3 = (v.w - mu) * rsig * gv.w + bv.w;

    const int b  = row >> 11;
    const int sl = row & (SEQ - 1);
    const int h  = tid >> 4;
    const size_t obase = (((size_t)(b*NH + h)) * SEQ + sl) * DEPTH + (tid & 15) * 4;

    if constexpr (MODE == 2) {
        unsigned w0 = (unsigned)f2bf(y0) | ((unsigned)f2bf(y1) << 16);
        unsigned w1 = (unsigned)f2bf(y2) | ((unsigned)f2bf(y3) << 16);
        *(uint2*)&OA[obase] = make_uint2(w0, w1);
    } else {
        float mx = fmaxf(fmaxf(y0, y1), fmaxf(y2, y3));
#pragma unroll
        for (int m = 1; m < 16; m <<= 1) mx = fmaxf(mx, __shfl_xor(mx, m, 16));
        float e0 = expf(y0 - mx), e1 = expf(y1 - mx), e2 = expf(y2 - mx), e3 = expf(y3 - mx);
        float se = e0 + e1 + e2 + e3;
#pragma unroll
        for (int m = 1; m < 16; m <<= 1) se += __shfl_xor(se, m, 16);
        float inv = 1.0f / se;
        float p0 = e0*inv, p1 = e1*inv, p2 = e2*inv, p3 = e3*inv;
        float o0, o1, o2, o3;
        if constexpr (MODE == 0) { o0 = p0; o1 = p1; o2 = p2; o3 = p3; }
        else {
            o0 = logf(p0 + 2e-8f); o1 = logf(p1 + 2e-8f);
            o2 = logf(p2 + 2e-8f); o3 = logf(p3 + 2e-8f);
        }
        u16 h0 = f2bf(o0), h1 = f2bf(o1), h2 = f2bf(o2), h3 = f2bf(o3);
        unsigned w0 = (unsigned)h0 | ((unsigned)h1 << 16);
        unsigned w1 = (unsigned)h2 | ((unsigned)h3 << 16);
        *(uint2*)&OA[obase] = make_uint2(w0, w1);
        u16 l0 = f2bf(o0 - bf2f(h0)), l1 = f2bf(o1 - bf2f(h1));
        u16 l2 = f2bf(o2 - bf2f(h2)), l3 = f2bf(o3 - bf2f(h3));
        w0 = (unsigned)l0 | ((unsigned)l1 << 16);
        w1 = (unsigned)l2 | ((unsigned)l3 << 16);
        *(uint2*)&OB[obase] = make_uint2(w0, w1);

        if constexpr (MODE == 0) {
            float lse = logf(se);
            float el = p0*(y0-mx-lse) + p1*(y1-mx-lse) + p2*(y2-mx-lse) + p3*(y3-mx-lse);
#pragma unroll
            for (int m = 1; m < 16; m <<= 1) el += __shfl_xor(el, m, 16);
            if ((tid & 15) == 0) ENT[((size_t)(b*NH + h)) * SEQ + sl] = el;
        }
    }
}

// ---------------------------------------------------------------------------
// V transpose via LDS: Vb [bh][s][d] bf16 -> VT [bh][d][s] bf16 (coalesced)
// Block = (s-chunk of 256, bh). Tile 256x64 u16.
// ---------------------------------------------------------------------------
__global__ __launch_bounds__(256) void vtrans_kernel(
    const u16* __restrict__ Vb, u16* __restrict__ VT)
{
    __shared__ u16 T[256*72];
    const int bh = blockIdx.y;
    const int s0 = blockIdx.x * 256;
    const int t  = threadIdx.x;
#pragma unroll
    for (int i = 0; i < 8; ++i) {
        int c = i*256 + t;                  // 0..2047
        int s = c >> 3, d0 = (c & 7) * 8;
        *(short8v*)&T[s*72 + d0] =
            *(const short8v*)&Vb[((size_t)bh*SEQ + s0 + s)*DEPTH + d0];
    }
    __syncthreads();
#pragma unroll
    for (int i = 0; i < 8; ++i) {
        int c = i*256 + t;                  // 0..2047
        int d = c >> 5, sl0 = (c & 31) * 8;
        short8v v;
#pragma unroll
        for (int j = 0; j < 8; ++j) v[j] = (short)T[(sl0 + j)*72 + d];
        *(short8v*)&VT[((size_t)bh*DEPTH + d)*SEQ + s0 + sl0] = v;
    }
}

// ---------------------------------------------------------------------------
// attn4: MFMA attention, two-phase, swizzled LDS, fast csch, Q in registers.
// Block: 64 q rows, 4 waves, k chunks of 64.
// ---------------------------------------------------------------------------
__global__ __launch_bounds__(256, 4) void attn4_kernel(
    const u16* __restrict__ QPh, const u16* __restrict__ QPl,
    const u16* __restrict__ LKh, const u16* __restrict__ LKl,
    const u16* __restrict__ VT, const float* __restrict__ ENT,
    float* __restrict__ ATTN, u16* __restrict__ OH, u16* __restrict__ OL)
{
    const int bh = blockIdx.y;
    const int q0 = blockIdx.x * 64;
    const int t  = threadIdx.x;
    const int l  = t & 63, w = t >> 6;
    const int lr = l & 15, lg = l >> 4;
    const size_t rbase = (size_t)bh * SEQ;

    __shared__ u16 KhS[64*64], KlS[64*64], VtS[64*64], PS[64*64];

    // Q fragments + entropy direct from global (loop-invariant)
    short8v qh[2], ql[2];
#pragma unroll
    for (int d = 0; d < 2; ++d) {
        size_t g = (rbase + q0 + w*16 + lr) * DEPTH + d*32 + lg*8;
        qh[d] = *(const short8v*)&QPh[g];
        ql[d] = *(const short8v*)&QPl[g];
    }
    float e8[4];
#pragma unroll
    for (int r = 0; r < 4; ++r)
        e8[r] = ENT[rbase + q0 + w*16 + lg*4 + r] * 0.125f;

    // ---------------- phase A: rowsums ----------------
    float rs[4] = {0.f, 0.f, 0.f, 0.f};
    for (int k0 = 0; k0 < SEQ; k0 += 64) {
        if (k0) __syncthreads();
#pragma unroll
        for (int r = 0; r < 2; ++r) {
            int s = r*256 + t; int kr = s >> 3, cb = (s & 7) * 16;
            size_t g = (rbase + k0 + kr) * DEPTH + (s & 7) * 8;
            *(short8v*)((char*)KhS + SWZ(kr, cb)) = *(const short8v*)&LKh[g];
            *(short8v*)((char*)KlS + SWZ(kr, cb)) = *(const short8v*)&LKl[g];
        }
        __syncthreads();

        f32x4 acc[4];
#pragma unroll
        for (int f = 0; f < 4; ++f) acc[f] = (f32x4){0.f,0.f,0.f,0.f};
        __builtin_amdgcn_s_setprio(1);
#pragma unroll
        for (int f = 0; f < 4; ++f)
#pragma unroll
            for (int d = 0; d < 2; ++d) {
                int off = SWZ(f*16 + lr, d*64 + lg*16);
                short8v kbh = *(const short8v*)((const char*)KhS + off);
                short8v kbl = *(const short8v*)((const char*)KlS + off);
                acc[f] = __builtin_amdgcn_mfma_f32_16x16x32_bf16(qh[d], kbh, acc[f], 0, 0, 0);
                acc[f] = __builtin_amdgcn_mfma_f32_16x16x32_bf16(qh[d], kbl, acc[f], 0, 0, 0);
                acc[f] = __builtin_amdgcn_mfma_f32_16x16x32_bf16(ql[d], kbh, acc[f], 0, 0, 0);
            }
        __builtin_amdgcn_s_setprio(0);
#pragma unroll
        for (int f = 0; f < 4; ++f)
#pragma unroll
            for (int r = 0; r < 4; ++r)
                rs[r] += fast_csch(fmaf(acc[f][r], -0.125f, e8[r]));
    }
#pragma unroll
    for (int m = 1; m < 16; m <<= 1)
#pragma unroll
        for (int r = 0; r < 4; ++r) rs[r] += __shfl_xor(rs[r], m, 16);
    float inv[4];
#pragma unroll
    for (int r = 0; r < 4; ++r) inv[r] = 1.0f / rs[r];

    // ---------------- phase B: normalized write + PV ----------------
    f32x4 av[4];
#pragma unroll
    for (int nf = 0; nf < 4; ++nf) av[nf] = (f32x4){0.f,0.f,0.f,0.f};

    for (int k0 = 0; k0 < SEQ; k0 += 64) {
        __syncthreads();
#pragma unroll
        for (int r = 0; r < 2; ++r) {
            int s = r*256 + t; int kr = s >> 3, cb = (s & 7) * 16;
            size_t g = (rbase + k0 + kr) * DEPTH + (s & 7) * 8;
            *(short8v*)((char*)KhS + SWZ(kr, cb)) = *(const short8v*)&LKh[g];
            *(short8v*)((char*)KlS + SWZ(kr, cb)) = *(const short8v*)&LKl[g];
        }
#pragma unroll
        for (int r = 0; r < 2; ++r) {
            int s = r*256 + t; int dd = s >> 3, cb = (s & 7) * 16;
            *(short8v*)((char*)VtS + SWZ(dd, cb)) =
                *(const short8v*)&VT[((size_t)bh * DEPTH + dd) * SEQ + k0 + (s & 7) * 8];
        }
        __syncthreads();

        f32x4 acc[4];
#pragma unroll
        for (int f = 0; f < 4; ++f) acc[f] = (f32x4){0.f,0.f,0.f,0.f};
        __builtin_amdgcn_s_setprio(1);
#pragma unroll
        for (int f = 0; f < 4; ++f)
#pragma unroll
            for (int d = 0; d < 2; ++d) {
                int off = SWZ(f*16 + lr, d*64 + lg*16);
                short8v kbh = *(const short8v*)((const char*)KhS + off);
                short8v kbl = *(const short8v*)((const char*)KlS + off);
                acc[f] = __builtin_amdgcn_mfma_f32_16x16x32_bf16(qh[d], kbh, acc[f], 0, 0, 0);
                acc[f] = __builtin_amdgcn_mfma_f32_16x16x32_bf16(qh[d], kbl, acc[f], 0, 0, 0);
                acc[f] = __builtin_amdgcn_mfma_f32_16x16x32_bf16(ql[d], kbh, acc[f], 0, 0, 0);
            }
        __builtin_amdgcn_s_setprio(0);

#pragma unroll
        for (int f = 0; f < 4; ++f)
#pragma unroll
            for (int r = 0; r < 4; ++r) {
                float c = fast_csch(fmaf(acc[f][r], -0.125f, e8[r]));
                float a = c * inv[r];
                int q = w*16 + lg*4 + r;
                ATTN[(rbase + q0 + q) * SEQ + k0 + f*16 + lr] = a;
                *(u16*)((char*)PS + SWZ(q, (f*16 + lr)*2)) = f2bf(a);
            }
        __syncthreads();

        short8v pa[2];
#pragma unroll
        for (int ks = 0; ks < 2; ++ks)
            pa[ks] = *(const short8v*)((const char*)PS + SWZ(w*16 + lr, ks*64 + lg*16));
        __builtin_amdgcn_s_setprio(1);
#pragma unroll
        for (int nf = 0; nf < 4; ++nf)
#pragma unroll
            for (int ks = 0; ks < 2; ++ks) {
                short8v vb = *(const short8v*)((const char*)VtS + SWZ(nf*16 + lr, ks*64 + lg*16));
                av[nf] = __builtin_amdgcn_mfma_f32_16x16x32_bf16(pa[ks], vb, av[nf], 0, 0, 0);
            }
        __builtin_amdgcn_s_setprio(0);
    }

    // OV write: normalized, (B,S,DM) layout, split bf16
    const int b = bh >> 4, h = bh & (NH - 1);
#pragma unroll
    for (int nf = 0; nf < 4; ++nf)
#pragma unroll
        for (int r = 0; r < 4; ++r) {
            int q = w*16 + lg*4 + r;
            int d = nf*16 + lr;
            size_t o = ((size_t)(b * SEQ + q0 + q)) * DM + h * DEPTH + d;
            float v = av[nf][r];
            u16 hh = f2bf(v);
            OH[o] = hh;
            OL[o] = f2bf(v - bf2f(hh));
        }
}

// ---------------------------------------------------------------------------
extern "C" void kernel_launch(void* const* d_in, const int* in_sizes, int n_in,
                              void* d_out, int out_size, void* d_ws, size_t ws_size,
                              hipStream_t stream)
{
    const float* q_in = (const float*)d_in[0];
    const float* k_in = (const float*)d_in[1];
    const float* Wq = (const float*)d_in[2];
    const float* bq = (const float*)d_in[3];
    const float* Wk = (const float*)d_in[4];
    const float* bk = (const float*)d_in[5];
    const float* Wv = (const float*)d_in[6];
    const float* bvp = (const float*)d_in[7];
    const float* Wo = (const float*)d_in[8];
    const float* bo = (const float*)d_in[9];
    const float* g1 = (const float*)d_in[10];
    const float* b1 = (const float*)d_in[11];
    const float* g2 = (const float*)d_in[12];
    const float* b2 = (const float*)d_in[13];
    const float* g3 = (const float*)d_in[14];
    const float* b3 = (const float*)d_in[15];

    float* out0 = (float*)d_out;                     // (B,S,DM)
    float* attn = out0 + (size_t)ROWS * DM;          // (B,H,S,S)

    char* base = (char*)d_ws;
    const size_t SLOT = (size_t)ROWS * DM * 4;       // 16 MB
    const size_t HALF = (size_t)ROWS * DM;           // 4M u16 elements
    float* S0f = (float*)(base);
    float* S1f = (float*)(base + SLOT);
    float* S2f = (float*)(base + 2*SLOT);
    float* S3f = (float*)(base + 3*SLOT);
    u16* S0h = (u16*)S0f; u16* S0l = S0h + HALF;
    u16* S1h = (u16*)S1f; u16* S1l = S1h + HALF;
    u16* S3h = (u16*)S3f; u16* S3l = S3h + HALF;
    // attention operand views
    u16* QPh = (u16*)S3f; u16* QPl = QPh + HALF;
    u16* LKh = (u16*)S2f; u16* LKl = LKh + HALF;
    u16* Vb  = (u16*)S0f; u16* VTp = Vb + HALF;
    u16* OHp = (u16*)S1f; u16* OLp = OHp + HALF;

    char* wbase = base + 4*SLOT;
    const size_t WSZ = (size_t)DM * DM * 2;          // 2 MB per bf16 matrix
    u16* WqH = (u16*)(wbase);           u16* WqL = (u16*)(wbase + WSZ);
    u16* WkH = (u16*)(wbase + 2*WSZ);   u16* WkL = (u16*)(wbase + 3*WSZ);
    u16* WvH = (u16*)(wbase + 4*WSZ);   u16* WvL = (u16*)(wbase + 5*WSZ);
    u16* WoH = (u16*)(wbase + 6*WSZ);   u16* WoL = (u16*)(wbase + 7*WSZ);
    float* ent = (float*)(wbase + 8*WSZ);

    const dim3 wgrid(32, 32);
    const dim3 ggrid(DM/64, ROWS/128);               // (16, 32)

    wsplit_kernel<<<wgrid, 256, 0, stream>>>(Wq, WqH, WqL);
    wsplit_kernel<<<wgrid, 256, 0, stream>>>(Wk, WkH, WkL);
    wsplit_kernel<<<wgrid, 256, 0, stream>>>(Wv, WvH, WvL);
    wsplit_kernel<<<wgrid, 256, 0, stream>>>(Wo, WoH, WoL);

    // q chain: q1 = q_in@Wq+bq (split ->S1), q2 = q1@Wq+bq (fp32 ->S2)
    split_kernel<<<ROWS*DM/(4*256), 256, 0, stream>>>(q_in, S0h, S0l);
    gemm_mfma<1><<<ggrid, 256, 0, stream>>>(S0h, S0l, WqH, WqL, bq, nullptr, S1h, S1l);
    gemm_mfma<0><<<ggrid, 256, 0, stream>>>(S1h, S1l, WqH, WqL, bq, S2f, nullptr, nullptr);
    // k chain: k1 (split ->S3), k2 (fp32 ->S0), v1 (fp32 ->S1)
    split_kernel<<<ROWS*DM/(4*256), 256, 0, stream>>>(k_in, S0h, S0l);
    gemm_mfma<1><<<ggrid, 256, 0, stream>>>(S0h, S0l, WkH, WkL, bk, nullptr, S3h, S3l);
    gemm_mfma<0><<<ggrid, 256, 0, stream>>>(S3h, S3l, WkH, WkL, bk, S0f, nullptr, nullptr);
    gemm_mfma<0><<<ggrid, 256, 0, stream>>>(S3h, S3l, WvH, WvL, bvp, S1f, nullptr, nullptr);

    // LN + head softmax -> bf16 BHSD operands
    ln_head_kernel<0><<<ROWS, 256, 0, stream>>>(S2f, g1, b1, QPh, QPl, ent);
    ln_head_kernel<1><<<ROWS, 256, 0, stream>>>(S0f, g2, b2, LKh, LKl, nullptr);
    ln_head_kernel<2><<<ROWS, 256, 0, stream>>>(S1f, g3, b3, Vb, nullptr, nullptr);
    vtrans_kernel<<<dim3(SEQ/256, BS*NH), 256, 0, stream>>>(Vb, VTp);

    // fused attention (normalized attn + normalized split OV)
    attn4_kernel<<<dim3(SEQ/64, BS*NH), 256, 0, stream>>>(
        QPh, QPl, LKh, LKl, VTp, ent, attn, OHp, OLp);

    // final projection
    gemm_mfma<0><<<ggrid, 256, 0, stream>>>(OHp, OLp, WoH, WoL, bo, out0, nullptr, nullptr);
}

// Round 5
// 581.195 us; speedup vs baseline: 2.9036x; 1.0697x over previous
//
#include <hip/hip_runtime.h>
#include <cstddef>
#include <cstdint>

#define BS      2
#define SEQ     2048
#define DM      1024
#define NH      16
#define DEPTH   64
#define ROWS    (BS*SEQ)          // 4096
#define BHS     (BS*NH*SEQ)       // 65536

typedef unsigned short u16;
typedef __attribute__((ext_vector_type(8))) short short8v;
typedef __attribute__((ext_vector_type(4))) float f32x4;

// swizzled byte offset into a [64 rows][128 B] LDS tile (T2 / G4 fix)
#define SWZ(row, cb) ((((row) << 7)) | ((cb) ^ (((row) & 7) << 4)))

__device__ __forceinline__ u16 f2bf(float x) {
    unsigned u = __builtin_bit_cast(unsigned, x);
    unsigned r = u + 0x7FFFu + ((u >> 16) & 1u);
    return (u16)(r >> 16);
}
__device__ __forceinline__ float bf2f(u16 h) {
    unsigned u = ((unsigned)h) << 16;
    return __builtin_bit_cast(float, u);
}

// fast csch(x)=1/sinh(x), ~9 ops / 2 transcendentals, no Newton steps.
// big path: 2t/(t^2-1), t=e^x (den via exact-ish fma, no cancellation).
// small path (|x|<0.04): 1/x - x/6  (truncation rel err < 1e-7).
__device__ __forceinline__ float fast_csch(float x) {
    float t    = __expf(x);
    float den  = fmaf(t, t, -1.0f);
    bool  sm   = fabsf(x) < 0.04f;
    float d    = sm ? x : den;
    float r    = __builtin_amdgcn_rcpf(d);
    float big  = 2.0f * t * r;
    float smal = fmaf(x, -(1.0f/6.0f), r);
    return sm ? smal : big;
}

// ---------------------------------------------------------------------------
// Weight transpose + split: W[K][N] fp32 -> Wt hi/lo [N][K] bf16
// ---------------------------------------------------------------------------
__global__ __launch_bounds__(256) void wsplit_kernel(
    const float* __restrict__ W, u16* __restrict__ H, u16* __restrict__ L)
{
    __shared__ float tile[32][33];
    const int bn = blockIdx.x, bk = blockIdx.y;
    const int c = threadIdx.x & 31, r0 = threadIdx.x >> 5;
#pragma unroll
    for (int r = 0; r < 32; r += 8)
        tile[r0 + r][c] = W[(size_t)(bk*32 + r0 + r) * DM + bn*32 + c];
    __syncthreads();
#pragma unroll
    for (int r = 0; r < 32; r += 8) {
        float v = tile[c][r0 + r];
        u16 h = f2bf(v);
        size_t o = (size_t)(bn*32 + r0 + r) * DM + bk*32 + c;
        H[o] = h;
        L[o] = f2bf(v - bf2f(h));
    }
}

// ---------------------------------------------------------------------------
// Elementwise split fp32 -> bf16 hi/lo
// ---------------------------------------------------------------------------
__global__ __launch_bounds__(256) void split_kernel(
    const float* __restrict__ X, u16* __restrict__ H, u16* __restrict__ L)
{
    int i = blockIdx.x * 256 + threadIdx.x;        // float4 index
    float4 v = ((const float4*)X)[i];
    u16 h0 = f2bf(v.x), h1 = f2bf(v.y), h2 = f2bf(v.z), h3 = f2bf(v.w);
    u16 l0 = f2bf(v.x - bf2f(h0)), l1 = f2bf(v.y - bf2f(h1));
    u16 l2 = f2bf(v.z - bf2f(h2)), l3 = f2bf(v.w - bf2f(h3));
    uint2 hh, ll;
    hh.x = (unsigned)h0 | ((unsigned)h1 << 16); hh.y = (unsigned)h2 | ((unsigned)h3 << 16);
    ll.x = (unsigned)l0 | ((unsigned)l1 << 16); ll.y = (unsigned)l2 | ((unsigned)l3 << 16);
    ((uint2*)H)[i] = hh;
    ((uint2*)L)[i] = ll;
}

// ---------------------------------------------------------------------------
// Split-bf16 MFMA GEMM: C = A@W + bias
// ---------------------------------------------------------------------------
template<int OUT_MODE>
__global__ __launch_bounds__(256) void gemm_mfma(
    const u16* __restrict__ Ah, const u16* __restrict__ Al,
    const u16* __restrict__ Bh, const u16* __restrict__ Bl,
    const float* __restrict__ bias, float* __restrict__ C,
    u16* __restrict__ Ch, u16* __restrict__ Cl)
{
    constexpr int K = 1024, N = 1024;
    __shared__ u16 AsH[128*40], AsL[128*40], BsH[64*40], BsL[64*40];

    const int t = threadIdx.x;
    const int m0 = blockIdx.y * 128;
    const int n0 = blockIdx.x * 64;
    const int lane = t & 63, w = t >> 6;
    const int wr = w >> 1, wc = w & 1;
    const int lr = lane & 15, lk = lane >> 4;

    f32x4 acc[4][2];
#pragma unroll
    for (int i = 0; i < 4; ++i)
#pragma unroll
        for (int j = 0; j < 2; ++j) acc[i][j] = (f32x4){0.f,0.f,0.f,0.f};

    for (int k0 = 0; k0 < K; k0 += 32) {
        __syncthreads();
#pragma unroll
        for (int r = 0; r < 2; ++r) {
            int s = r*256 + t;
            int row = s >> 2, c = s & 3;
            size_t g = (size_t)(m0 + row) * K + k0 + c*8;
            *(short8v*)&AsH[row*40 + c*8] = *(const short8v*)&Ah[g];
            *(short8v*)&AsL[row*40 + c*8] = *(const short8v*)&Al[g];
        }
        {
            int row = t >> 2, c = t & 3;
            size_t g = (size_t)(n0 + row) * K + k0 + c*8;
            *(short8v*)&BsH[row*40 + c*8] = *(const short8v*)&Bh[g];
            *(short8v*)&BsL[row*40 + c*8] = *(const short8v*)&Bl[g];
        }
        __syncthreads();

        short8v ah[4], al[4], bh[2], bl[2];
#pragma unroll
        for (int i = 0; i < 4; ++i) {
            int off = (wr*64 + i*16 + lr)*40 + lk*8;
            ah[i] = *(const short8v*)&AsH[off];
            al[i] = *(const short8v*)&AsL[off];
        }
#pragma unroll
        for (int j = 0; j < 2; ++j) {
            int off = (wc*32 + j*16 + lr)*40 + lk*8;
            bh[j] = *(const short8v*)&BsH[off];
            bl[j] = *(const short8v*)&BsL[off];
        }
        __builtin_amdgcn_s_setprio(1);
#pragma unroll
        for (int i = 0; i < 4; ++i)
#pragma unroll
            for (int j = 0; j < 2; ++j) {
                acc[i][j] = __builtin_amdgcn_mfma_f32_16x16x32_bf16(ah[i], bh[j], acc[i][j], 0, 0, 0);
                acc[i][j] = __builtin_amdgcn_mfma_f32_16x16x32_bf16(ah[i], bl[j], acc[i][j], 0, 0, 0);
                acc[i][j] = __builtin_amdgcn_mfma_f32_16x16x32_bf16(al[i], bh[j], acc[i][j], 0, 0, 0);
            }
        __builtin_amdgcn_s_setprio(0);
    }

    float bj[2];
#pragma unroll
    for (int j = 0; j < 2; ++j) bj[j] = bias[n0 + wc*32 + j*16 + lr];
#pragma unroll
    for (int i = 0; i < 4; ++i)
#pragma unroll
        for (int j = 0; j < 2; ++j) {
            int col = n0 + wc*32 + j*16 + lr;
#pragma unroll
            for (int r = 0; r < 4; ++r) {
                int row = m0 + wr*64 + i*16 + lk*4 + r;
                float v = acc[i][j][r] + bj[j];
                size_t o = (size_t)row * N + col;
                if constexpr (OUT_MODE == 0) {
                    C[o] = v;
                } else {
                    u16 h = f2bf(v);
                    Ch[o] = h;
                    Cl[o] = f2bf(v - bf2f(h));
                }
            }
        }
}

// ---------------------------------------------------------------------------
// Fused LayerNorm -> per-head softmax; bf16 outputs in BHSD layout.
// MODE 0: OA/OB = q_prob hi/lo + ENT ; MODE 1: OA/OB = log(prob+eps) hi/lo ;
// MODE 2: OA = LN result bf16 (single).
// ---------------------------------------------------------------------------
template<int MODE>
__global__ __launch_bounds__(256) void ln_head_kernel(
    const float* __restrict__ X, const float* __restrict__ G,
    const float* __restrict__ Bt, u16* __restrict__ OA,
    u16* __restrict__ OB, float* __restrict__ ENT)
{
    const int row = blockIdx.x;
    const int tid = threadIdx.x;
    const float* x = X + (size_t)row * DM;
    float4 v = *(const float4*)&x[tid*4];

    float s  = v.x + v.y + v.z + v.w;
    float ss = v.x*v.x + v.y*v.y + v.z*v.z + v.w*v.w;
#pragma unroll
    for (int m = 1; m < 64; m <<= 1) { s += __shfl_xor(s, m); ss += __shfl_xor(ss, m); }
    __shared__ float redS[4], redQ[4];
    const int wave = tid >> 6, lane = tid & 63;
    if (lane == 0) { redS[wave] = s; redQ[wave] = ss; }
    __syncthreads();
    s  = redS[0] + redS[1] + redS[2] + redS[3];
    ss = redQ[0] + redQ[1] + redQ[2] + redQ[3];
    const float mu   = s * (1.0f / DM);
    const float var  = ss * (1.0f / DM) - mu * mu;
    const float rsig = rsqrtf(var + 1e-6f);

    float4 gv = *(const float4*)&G[tid*4];
    float4 bv = *(const float4*)&Bt[tid*4];
    float y0 = (v.x - mu) * rsig * gv.x + bv.x;
    float y1 = (v.y - mu) * rsig * gv.y + bv.y;
    float y2 = (v.z - mu) * rsig * gv.z + bv.z;
    float y3 = (v.w - mu) * rsig * gv.w + bv.w;

    const int b  = row >> 11;
    const int sl = row & (SEQ - 1);
    const int h  = tid >> 4;
    const size_t obase = (((size_t)(b*NH + h)) * SEQ + sl) * DEPTH + (tid & 15) * 4;

    if constexpr (MODE == 2) {
        unsigned w0 = (unsigned)f2bf(y0) | ((unsigned)f2bf(y1) << 16);
        unsigned w1 = (unsigned)f2bf(y2) | ((unsigned)f2bf(y3) << 16);
        *(uint2*)&OA[obase] = make_uint2(w0, w1);
    } else {
        float mx = fmaxf(fmaxf(y0, y1), fmaxf(y2, y3));
#pragma unroll
        for (int m = 1; m < 16; m <<= 1) mx = fmaxf(mx, __shfl_xor(mx, m, 16));
        float e0 = expf(y0 - mx), e1 = expf(y1 - mx), e2 = expf(y2 - mx), e3 = expf(y3 - mx);
        float se = e0 + e1 + e2 + e3;
#pragma unroll
        for (int m = 1; m < 16; m <<= 1) se += __shfl_xor(se, m, 16);
        float inv = 1.0f / se;
        float p0 = e0*inv, p1 = e1*inv, p2 = e2*inv, p3 = e3*inv;
        float o0, o1, o2, o3;
        if constexpr (MODE == 0) { o0 = p0; o1 = p1; o2 = p2; o3 = p3; }
        else {
            o0 = logf(p0 + 2e-8f); o1 = logf(p1 + 2e-8f);
            o2 = logf(p2 + 2e-8f); o3 = logf(p3 + 2e-8f);
        }
        u16 h0 = f2bf(o0), h1 = f2bf(o1), h2 = f2bf(o2), h3 = f2bf(o3);
        unsigned w0 = (unsigned)h0 | ((unsigned)h1 << 16);
        unsigned w1 = (unsigned)h2 | ((unsigned)h3 << 16);
        *(uint2*)&OA[obase] = make_uint2(w0, w1);
        u16 l0 = f2bf(o0 - bf2f(h0)), l1 = f2bf(o1 - bf2f(h1));
        u16 l2 = f2bf(o2 - bf2f(h2)), l3 = f2bf(o3 - bf2f(h3));
        w0 = (unsigned)l0 | ((unsigned)l1 << 16);
        w1 = (unsigned)l2 | ((unsigned)l3 << 16);
        *(uint2*)&OB[obase] = make_uint2(w0, w1);

        if constexpr (MODE == 0) {
            float lse = logf(se);
            float el = p0*(y0-mx-lse) + p1*(y1-mx-lse) + p2*(y2-mx-lse) + p3*(y3-mx-lse);
#pragma unroll
            for (int m = 1; m < 16; m <<= 1) el += __shfl_xor(el, m, 16);
            if ((tid & 15) == 0) ENT[((size_t)(b*NH + h)) * SEQ + sl] = el;
        }
    }
}

// ---------------------------------------------------------------------------
// V transpose via LDS: Vb [bh][s][d] bf16 -> VT [bh][d][s] bf16 (coalesced)
// ---------------------------------------------------------------------------
__global__ __launch_bounds__(256) void vtrans_kernel(
    const u16* __restrict__ Vb, u16* __restrict__ VT)
{
    __shared__ u16 T[256*72];
    const int bh = blockIdx.y;
    const int s0 = blockIdx.x * 256;
    const int t  = threadIdx.x;
#pragma unroll
    for (int i = 0; i < 8; ++i) {
        int c = i*256 + t;                  // 0..2047
        int s = c >> 3, d0 = (c & 7) * 8;
        *(short8v*)&T[s*72 + d0] =
            *(const short8v*)&Vb[((size_t)bh*SEQ + s0 + s)*DEPTH + d0];
    }
    __syncthreads();
#pragma unroll
    for (int i = 0; i < 8; ++i) {
        int c = i*256 + t;                  // 0..2047
        int d = c >> 5, sl0 = (c & 31) * 8;
        short8v v;
#pragma unroll
        for (int j = 0; j < 8; ++j) v[j] = (short)T[(sl0 + j)*72 + d];
        *(short8v*)&VT[((size_t)bh*DEPTH + d)*SEQ + s0 + sl0] = v;
    }
}

// ---------------------------------------------------------------------------
// attn5: MFMA attention, two-phase, swizzled LDS, cheap csch, Q in regs,
// XCD-chunked 1D grid, 2 barriers/chunk (PS is intra-wave).
// ---------------------------------------------------------------------------
__global__ __launch_bounds__(256, 4) void attn5_kernel(
    const u16* __restrict__ QPh, const u16* __restrict__ QPl,
    const u16* __restrict__ LKh, const u16* __restrict__ LKl,
    const u16* __restrict__ VT, const float* __restrict__ ENT,
    float* __restrict__ ATTN, u16* __restrict__ OH, u16* __restrict__ OL)
{
    // XCD-aware bijective swizzle: 1024 wgs, 8 XCDs, 128 contiguous per XCD
    // -> each XCD owns 4 consecutive bh (K/V ~3 MB resident in its L2).
    const int wg   = blockIdx.x;
    const int wgid = (wg & 7) * 128 + (wg >> 3);
    const int bh   = wgid >> 5;
    const int q0   = (wgid & 31) * 64;

    const int t  = threadIdx.x;
    const int l  = t & 63, w = t >> 6;
    const int lr = l & 15, lg = l >> 4;
    const size_t rbase = (size_t)bh * SEQ;

    __shared__ u16 KhS[64*64], KlS[64*64], VtS[64*64], PS[64*64];

    // Q fragments + entropy direct from global (loop-invariant)
    short8v qh[2], ql[2];
#pragma unroll
    for (int d = 0; d < 2; ++d) {
        size_t g = (rbase + q0 + w*16 + lr) * DEPTH + d*32 + lg*8;
        qh[d] = *(const short8v*)&QPh[g];
        ql[d] = *(const short8v*)&QPl[g];
    }
    float e8[4];
#pragma unroll
    for (int r = 0; r < 4; ++r)
        e8[r] = ENT[rbase + q0 + w*16 + lg*4 + r] * 0.125f;

    // ---------------- phase A: rowsums ----------------
    float rs[4] = {0.f, 0.f, 0.f, 0.f};
    for (int k0 = 0; k0 < SEQ; k0 += 64) {
        if (k0) __syncthreads();
#pragma unroll
        for (int r = 0; r < 2; ++r) {
            int s = r*256 + t; int kr = s >> 3, cb = (s & 7) * 16;
            size_t g = (rbase + k0 + kr) * DEPTH + (s & 7) * 8;
            *(short8v*)((char*)KhS + SWZ(kr, cb)) = *(const short8v*)&LKh[g];
            *(short8v*)((char*)KlS + SWZ(kr, cb)) = *(const short8v*)&LKl[g];
        }
        __syncthreads();

        f32x4 acc[4];
#pragma unroll
        for (int f = 0; f < 4; ++f) acc[f] = (f32x4){0.f,0.f,0.f,0.f};
        __builtin_amdgcn_s_setprio(1);
#pragma unroll
        for (int f = 0; f < 4; ++f)
#pragma unroll
            for (int d = 0; d < 2; ++d) {
                int off = SWZ(f*16 + lr, d*64 + lg*16);
                short8v kbh = *(const short8v*)((const char*)KhS + off);
                short8v kbl = *(const short8v*)((const char*)KlS + off);
                acc[f] = __builtin_amdgcn_mfma_f32_16x16x32_bf16(qh[d], kbh, acc[f], 0, 0, 0);
                acc[f] = __builtin_amdgcn_mfma_f32_16x16x32_bf16(qh[d], kbl, acc[f], 0, 0, 0);
                acc[f] = __builtin_amdgcn_mfma_f32_16x16x32_bf16(ql[d], kbh, acc[f], 0, 0, 0);
            }
        __builtin_amdgcn_s_setprio(0);
#pragma unroll
        for (int f = 0; f < 4; ++f)
#pragma unroll
            for (int r = 0; r < 4; ++r)
                rs[r] += fast_csch(fmaf(acc[f][r], -0.125f, e8[r]));
    }
#pragma unroll
    for (int m = 1; m < 16; m <<= 1)
#pragma unroll
        for (int r = 0; r < 4; ++r) rs[r] += __shfl_xor(rs[r], m, 16);
    float inv[4];
#pragma unroll
    for (int r = 0; r < 4; ++r) inv[r] = 1.0f / rs[r];

    // ---------------- phase B: normalized write + PV ----------------
    f32x4 av[4];
#pragma unroll
    for (int nf = 0; nf < 4; ++nf) av[nf] = (f32x4){0.f,0.f,0.f,0.f};

    for (int k0 = 0; k0 < SEQ; k0 += 64) {
        __syncthreads();     // prior chunk's K/V LDS reads complete
#pragma unroll
        for (int r = 0; r < 2; ++r) {
            int s = r*256 + t; int kr = s >> 3, cb = (s & 7) * 16;
            size_t g = (rbase + k0 + kr) * DEPTH + (s & 7) * 8;
            *(short8v*)((char*)KhS + SWZ(kr, cb)) = *(const short8v*)&LKh[g];
            *(short8v*)((char*)KlS + SWZ(kr, cb)) = *(const short8v*)&LKl[g];
        }
#pragma unroll
        for (int r = 0; r < 2; ++r) {
            int s = r*256 + t; int dd = s >> 3, cb = (s & 7) * 16;
            *(short8v*)((char*)VtS + SWZ(dd, cb)) =
                *(const short8v*)&VT[((size_t)bh * DEPTH + dd) * SEQ + k0 + (s & 7) * 8];
        }
        __syncthreads();

        f32x4 acc[4];
#pragma unroll
        for (int f = 0; f < 4; ++f) acc[f] = (f32x4){0.f,0.f,0.f,0.f};
        __builtin_amdgcn_s_setprio(1);
#pragma unroll
        for (int f = 0; f < 4; ++f)
#pragma unroll
            for (int d = 0; d < 2; ++d) {
                int off = SWZ(f*16 + lr, d*64 + lg*16);
                short8v kbh = *(const short8v*)((const char*)KhS + off);
                short8v kbl = *(const short8v*)((const char*)KlS + off);
                acc[f] = __builtin_amdgcn_mfma_f32_16x16x32_bf16(qh[d], kbh, acc[f], 0, 0, 0);
                acc[f] = __builtin_amdgcn_mfma_f32_16x16x32_bf16(qh[d], kbl, acc[f], 0, 0, 0);
                acc[f] = __builtin_amdgcn_mfma_f32_16x16x32_bf16(ql[d], kbh, acc[f], 0, 0, 0);
            }
        __builtin_amdgcn_s_setprio(0);

        // csch + normalized ATTN write + PS (own-wave rows; no barrier needed)
#pragma unroll
        for (int f = 0; f < 4; ++f)
#pragma unroll
            for (int r = 0; r < 4; ++r) {
                float c = fast_csch(fmaf(acc[f][r], -0.125f, e8[r]));
                float a = c * inv[r];
                int q = w*16 + lg*4 + r;
                ATTN[(rbase + q0 + q) * SEQ + k0 + f*16 + lr] = a;
                *(u16*)((char*)PS + SWZ(q, (f*16 + lr)*2)) = f2bf(a);
            }

        short8v pa[2];
#pragma unroll
        for (int ks = 0; ks < 2; ++ks)
            pa[ks] = *(const short8v*)((const char*)PS + SWZ(w*16 + lr, ks*64 + lg*16));
        __builtin_amdgcn_s_setprio(1);
#pragma unroll
        for (int nf = 0; nf < 4; ++nf)
#pragma unroll
            for (int ks = 0; ks < 2; ++ks) {
                short8v vb = *(const short8v*)((const char*)VtS + SWZ(nf*16 + lr, ks*64 + lg*16));
                av[nf] = __builtin_amdgcn_mfma_f32_16x16x32_bf16(pa[ks], vb, av[nf], 0, 0, 0);
            }
        __builtin_amdgcn_s_setprio(0);
    }

    // OV write: normalized, (B,S,DM) layout, split bf16
    const int b = bh >> 4, h = bh & (NH - 1);
#pragma unroll
    for (int nf = 0; nf < 4; ++nf)
#pragma unroll
        for (int r = 0; r < 4; ++r) {
            int q = w*16 + lg*4 + r;
            int d = nf*16 + lr;
            size_t o = ((size_t)(b * SEQ + q0 + q)) * DM + h * DEPTH + d;
            float v = av[nf][r];
            u16 hh = f2bf(v);
            OH[o] = hh;
            OL[o] = f2bf(v - bf2f(hh));
        }
}

// ---------------------------------------------------------------------------
extern "C" void kernel_launch(void* const* d_in, const int* in_sizes, int n_in,
                              void* d_out, int out_size, void* d_ws, size_t ws_size,
                              hipStream_t stream)
{
    const float* q_in = (const float*)d_in[0];
    const float* k_in = (const float*)d_in[1];
    const float* Wq = (const float*)d_in[2];
    const float* bq = (const float*)d_in[3];
    const float* Wk = (const float*)d_in[4];
    const float* bk = (const float*)d_in[5];
    const float* Wv = (const float*)d_in[6];
    const float* bvp = (const float*)d_in[7];
    const float* Wo = (const float*)d_in[8];
    const float* bo = (const float*)d_in[9];
    const float* g1 = (const float*)d_in[10];
    const float* b1 = (const float*)d_in[11];
    const float* g2 = (const float*)d_in[12];
    const float* b2 = (const float*)d_in[13];
    const float* g3 = (const float*)d_in[14];
    const float* b3 = (const float*)d_in[15];

    float* out0 = (float*)d_out;                     // (B,S,DM)
    float* attn = out0 + (size_t)ROWS * DM;          // (B,H,S,S)

    char* base = (char*)d_ws;
    const size_t SLOT = (size_t)ROWS * DM * 4;       // 16 MB
    const size_t HALF = (size_t)ROWS * DM;           // 4M u16 elements
    float* S0f = (float*)(base);
    float* S1f = (float*)(base + SLOT);
    float* S2f = (float*)(base + 2*SLOT);
    float* S3f = (float*)(base + 3*SLOT);
    u16* S0h = (u16*)S0f; u16* S0l = S0h + HALF;
    u16* S1h = (u16*)S1f; u16* S1l = S1h + HALF;
    u16* S3h = (u16*)S3f; u16* S3l = S3h + HALF;
    // attention operand views
    u16* QPh = (u16*)S3f; u16* QPl = QPh + HALF;
    u16* LKh = (u16*)S2f; u16* LKl = LKh + HALF;
    u16* Vb  = (u16*)S0f; u16* VTp = Vb + HALF;
    u16* OHp = (u16*)S1f; u16* OLp = OHp + HALF;

    char* wbase = base + 4*SLOT;
    const size_t WSZ = (size_t)DM * DM * 2;          // 2 MB per bf16 matrix
    u16* WqH = (u16*)(wbase);           u16* WqL = (u16*)(wbase + WSZ);
    u16* WkH = (u16*)(wbase + 2*WSZ);   u16* WkL = (u16*)(wbase + 3*WSZ);
    u16* WvH = (u16*)(wbase + 4*WSZ);   u16* WvL = (u16*)(wbase + 5*WSZ);
    u16* WoH = (u16*)(wbase + 6*WSZ);   u16* WoL = (u16*)(wbase + 7*WSZ);
    float* ent = (float*)(wbase + 8*WSZ);

    const dim3 wgrid(32, 32);
    const dim3 ggrid(DM/64, ROWS/128);               // (16, 32)

    wsplit_kernel<<<wgrid, 256, 0, stream>>>(Wq, WqH, WqL);
    wsplit_kernel<<<wgrid, 256, 0, stream>>>(Wk, WkH, WkL);
    wsplit_kernel<<<wgrid, 256, 0, stream>>>(Wv, WvH, WvL);
    wsplit_kernel<<<wgrid, 256, 0, stream>>>(Wo, WoH, WoL);

    // q chain: q1 = q_in@Wq+bq (split ->S1), q2 = q1@Wq+bq (fp32 ->S2)
    split_kernel<<<ROWS*DM/(4*256), 256, 0, stream>>>(q_in, S0h, S0l);
    gemm_mfma<1><<<ggrid, 256, 0, stream>>>(S0h, S0l, WqH, WqL, bq, nullptr, S1h, S1l);
    gemm_mfma<0><<<ggrid, 256, 0, stream>>>(S1h, S1l, WqH, WqL, bq, S2f, nullptr, nullptr);
    // k chain: k1 (split ->S3), k2 (fp32 ->S0), v1 (fp32 ->S1)
    split_kernel<<<ROWS*DM/(4*256), 256, 0, stream>>>(k_in, S0h, S0l);
    gemm_mfma<1><<<ggrid, 256, 0, stream>>>(S0h, S0l, WkH, WkL, bk, nullptr, S3h, S3l);
    gemm_mfma<0><<<ggrid, 256, 0, stream>>>(S3h, S3l, WkH, WkL, bk, S0f, nullptr, nullptr);
    gemm_mfma<0><<<ggrid, 256, 0, stream>>>(S3h, S3l, WvH, WvL, bvp, S1f, nullptr, nullptr);

    // LN + head softmax -> bf16 BHSD operands
    ln_head_kernel<0><<<ROWS, 256, 0, stream>>>(S2f, g1, b1, QPh, QPl, ent);
    ln_head_kernel<1><<<ROWS, 256, 0, stream>>>(S0f, g2, b2, LKh, LKl, nullptr);
    ln_head_kernel<2><<<ROWS, 256, 0, stream>>>(S1f, g3, b3, Vb, nullptr, nullptr);
    vtrans_kernel<<<dim3(SEQ/256, BS*NH), 256, 0, stream>>>(Vb, VTp);

    // fused attention (normalized attn + normalized split OV)
    attn5_kernel<<<dim3(SEQ/64 * BS*NH), 256, 0, stream>>>(
        QPh, QPl, LKh, LKl, VTp, ent, attn, OHp, OLp);

    // final projection
    gemm_mfma<0><<<ggrid, 256, 0, stream>>>(OHp, OLp, WoH, WoL, bo, out0, nullptr, nullptr);
}